// Round 1
// baseline (10635.734 us; speedup 1.0000x reference)
//
#include <hip/hip_runtime.h>
#include <hip/hip_bf16.h>

// Problem constants
#define C_DIM   320
#define N_SP    2304      // 48*48
#define NHEADS  8
#define DHEAD   40
#define GROUPS  32
#define CPG     10        // C_DIM / GROUPS
#define BATCH   2

// -------------------------------------------------------------------------
// GroupNorm: one block per (b, g). Reduce 10*2304 = 23040 elements.
// -------------------------------------------------------------------------
__global__ __launch_bounds__(256) void gn_kernel(
    const float* __restrict__ x,
    const float* __restrict__ gamma,
    const float* __restrict__ beta,
    float* __restrict__ xn)
{
    const int b = blockIdx.x >> 5;
    const int g = blockIdx.x & 31;
    const size_t base = ((size_t)b * C_DIM + (size_t)g * CPG) * N_SP;
    const float* xp = x + base;
    float* xnp = xn + base;
    const int tid = threadIdx.x;
    const int tot = CPG * N_SP;

    float sum = 0.f, sumsq = 0.f;
    for (int idx = tid; idx < tot; idx += 256) {
        float v = xp[idx];
        sum += v;
        sumsq += v * v;
    }
    #pragma unroll
    for (int off = 32; off; off >>= 1) {
        sum   += __shfl_xor(sum, off);
        sumsq += __shfl_xor(sumsq, off);
    }
    __shared__ float red[2][4];
    const int w = tid >> 6;
    if ((tid & 63) == 0) { red[0][w] = sum; red[1][w] = sumsq; }
    __syncthreads();
    sum   = red[0][0] + red[0][1] + red[0][2] + red[0][3];
    sumsq = red[1][0] + red[1][1] + red[1][2] + red[1][3];

    const float inv_n = 1.0f / (float)tot;
    const float mean = sum * inv_n;
    const float var  = sumsq * inv_n - mean * mean;
    const float rstd = rsqrtf(var + 1e-5f);

    for (int idx = tid; idx < tot; idx += 256) {
        const int c = g * CPG + idx / N_SP;
        xnp[idx] = (xp[idx] - mean) * rstd * gamma[c] + beta[c];
    }
}

// -------------------------------------------------------------------------
// fp32 GEMM: Y[b,o,n] = bias[o] + sum_c W[o,c] * X[b,c,n]  (+ resid[b,o,n])
// W: [320,320] row-major. X,Y: [B,320,2304].
// Tile 64(o) x 64(n), TK=16, block 256 threads, 4x4 micro-tile per thread.
// grid: (N/64=36, O/64=5, B=2)
// -------------------------------------------------------------------------
__global__ __launch_bounds__(256) void gemm_kernel(
    const float* __restrict__ W,
    const float* __restrict__ bias,
    const float* __restrict__ X,
    float* __restrict__ Y,
    const float* __restrict__ resid)   // may be nullptr
{
    const int b  = blockIdx.z;
    const int n0 = blockIdx.x * 64;
    const int o0 = blockIdx.y * 64;

    __shared__ float Ws[16][65];  // Ws[k][o]
    __shared__ float Xs[16][65];  // Xs[k][n]

    const int tid = threadIdx.x;
    const int tx = tid & 15;        // n micro-tile index
    const int ty = tid >> 4;        // o micro-tile index (0..15)
    const size_t xbase = (size_t)b * C_DIM * N_SP;

    float acc[4][4];
    #pragma unroll
    for (int i = 0; i < 4; ++i)
        #pragma unroll
        for (int j = 0; j < 4; ++j) acc[i][j] = 0.f;

    for (int k0 = 0; k0 < C_DIM; k0 += 16) {
        // Load W tile: kk fastest for coalescing (W rows are contiguous in c)
        #pragma unroll
        for (int i = 0; i < 4; ++i) {
            const int idx = tid + i * 256;          // 0..1023
            const int kk = idx & 15;
            const int oo = idx >> 4;
            Ws[kk][oo] = W[(size_t)(o0 + oo) * C_DIM + (k0 + kk)];
        }
        // Load X tile: nn fastest (contiguous)
        #pragma unroll
        for (int i = 0; i < 4; ++i) {
            const int idx = tid + i * 256;
            const int kk = idx >> 6;
            const int nn = idx & 63;
            Xs[kk][nn] = X[xbase + (size_t)(k0 + kk) * N_SP + (n0 + nn)];
        }
        __syncthreads();
        #pragma unroll
        for (int k = 0; k < 16; ++k) {
            float wv[4], xv[4];
            #pragma unroll
            for (int i = 0; i < 4; ++i) wv[i] = Ws[k][ty * 4 + i];
            #pragma unroll
            for (int j = 0; j < 4; ++j) xv[j] = Xs[k][tx * 4 + j];
            #pragma unroll
            for (int i = 0; i < 4; ++i)
                #pragma unroll
                for (int j = 0; j < 4; ++j)
                    acc[i][j] += wv[i] * xv[j];
        }
        __syncthreads();
    }

    #pragma unroll
    for (int i = 0; i < 4; ++i) {
        const int o = o0 + ty * 4 + i;
        const float bo_ = bias[o];
        #pragma unroll
        for (int j = 0; j < 4; ++j) {
            const int n = n0 + tx * 4 + j;
            const size_t oidx = xbase + (size_t)o * N_SP + n;
            float r = resid ? resid[oidx] : 0.f;
            Y[oidx] = acc[i][j] + bo_ + r;
        }
    }
}

// -------------------------------------------------------------------------
// Attention: one 64-lane wave per query position i of one (b,h).
// q,k,v: [B, 320, N]; head h occupies channels h*40 .. h*40+39.
// Each lane owns j = lane, lane+64, ... (36 keys). Scores kept in registers.
// -------------------------------------------------------------------------
__global__ __launch_bounds__(256) void attn_kernel(
    const float* __restrict__ q,
    const float* __restrict__ k,
    const float* __restrict__ v,
    float* __restrict__ out)
{
    const int wave = (blockIdx.x * 256 + threadIdx.x) >> 6;
    const int lane = threadIdx.x & 63;

    const int i  = wave % N_SP;
    const int bh = wave / N_SP;
    const int h  = bh & 7;
    const int b  = bh >> 3;

    const float scale2 = 0.15811388300841897f;  // 1/sqrt(40)
    const size_t hbase = ((size_t)b * C_DIM + (size_t)h * DHEAD) * N_SP;
    const float* qp = q + hbase + i;
    const float* kp = k + hbase;
    const float* vp = v + hbase;

    float qr[DHEAD];
    #pragma unroll
    for (int dd = 0; dd < DHEAD; ++dd)
        qr[dd] = qp[(size_t)dd * N_SP] * scale2;

    // Pass 1: scores for this lane's 36 keys + running max
    float s[36];
    float m = -1e30f;
    #pragma unroll
    for (int jj = 0; jj < 36; ++jj) {
        const int j = jj * 64 + lane;
        float acc = 0.f;
        #pragma unroll
        for (int dd = 0; dd < DHEAD; ++dd)
            acc += qr[dd] * kp[(size_t)dd * N_SP + j];
        s[jj] = acc;
        m = fmaxf(m, acc);
    }
    #pragma unroll
    for (int off = 32; off; off >>= 1)
        m = fmaxf(m, __shfl_xor(m, off));

    // Pass 2: exp + PV accumulate
    float l = 0.f;
    float acc[DHEAD];
    #pragma unroll
    for (int dd = 0; dd < DHEAD; ++dd) acc[dd] = 0.f;
    #pragma unroll
    for (int jj = 0; jj < 36; ++jj) {
        const int j = jj * 64 + lane;
        const float p = __expf(s[jj] - m);
        l += p;
        #pragma unroll
        for (int dd = 0; dd < DHEAD; ++dd)
            acc[dd] += p * vp[(size_t)dd * N_SP + j];
    }
    #pragma unroll
    for (int off = 32; off; off >>= 1)
        l += __shfl_xor(l, off);
    const float inv = 1.0f / l;
    #pragma unroll
    for (int dd = 0; dd < DHEAD; ++dd) {
        float a = acc[dd];
        #pragma unroll
        for (int off = 32; off; off >>= 1)
            a += __shfl_xor(a, off);
        acc[dd] = a * inv;
    }

    if (lane == 0) {
        float* op = out + hbase + i;
        #pragma unroll
        for (int dd = 0; dd < DHEAD; ++dd)
            op[(size_t)dd * N_SP] = acc[dd];
    }
}

// -------------------------------------------------------------------------
extern "C" void kernel_launch(void* const* d_in, const int* in_sizes, int n_in,
                              void* d_out, int out_size, void* d_ws, size_t ws_size,
                              hipStream_t stream) {
    const float* x     = (const float*)d_in[0];
    const float* gamma = (const float*)d_in[1];
    const float* beta  = (const float*)d_in[2];
    const float* Wq    = (const float*)d_in[3];
    const float* bq    = (const float*)d_in[4];
    const float* Wk    = (const float*)d_in[5];
    const float* bk    = (const float*)d_in[6];
    const float* Wv    = (const float*)d_in[7];
    const float* bv    = (const float*)d_in[8];
    const float* Wo    = (const float*)d_in[9];
    const float* bo    = (const float*)d_in[10];

    float* out = (float*)d_out;
    float* ws  = (float*)d_ws;

    const size_t S = (size_t)BATCH * C_DIM * N_SP;  // 1,474,560 floats
    float* xn  = ws;
    float* q   = ws + S;
    float* k   = ws + 2 * S;
    float* v   = ws + 3 * S;
    float* att = ws + 4 * S;

    gn_kernel<<<BATCH * GROUPS, 256, 0, stream>>>(x, gamma, beta, xn);

    dim3 ggrid(N_SP / 64, C_DIM / 64, BATCH);  // (36, 5, 2)
    gemm_kernel<<<ggrid, 256, 0, stream>>>(Wq, bq, xn, q, nullptr);
    gemm_kernel<<<ggrid, 256, 0, stream>>>(Wk, bk, xn, k, nullptr);
    gemm_kernel<<<ggrid, 256, 0, stream>>>(Wv, bv, xn, v, nullptr);

    // 36864 query-waves, 4 waves per 256-thread block
    attn_kernel<<<(BATCH * NHEADS * N_SP) / 4, 256, 0, stream>>>(q, k, v, att);

    gemm_kernel<<<ggrid, 256, 0, stream>>>(Wo, bo, att, out, x);
}

// Round 2
// 365.560 us; speedup vs baseline: 29.0944x; 29.0944x over previous
//
#include <hip/hip_runtime.h>
#include <hip/hip_bf16.h>

#define C_DIM   320
#define N_SP    2304      // 48*48
#define NHEADS  8
#define DHEAD   40
#define GROUPS  32
#define CPG     10
#define BATCH   2
#define DPAD    64        // d padded for K=32 MFMA steps
#define VPAD    48        // v rows padded to 3x16

typedef __bf16 bf16x8 __attribute__((ext_vector_type(8)));
typedef float  f32x4  __attribute__((ext_vector_type(4)));

#define MFMA16(a, b, c) __builtin_amdgcn_mfma_f32_16x16x32_bf16((a), (b), (c), 0, 0, 0)

// -------------------------------------------------------------------------
// GroupNorm: one block per (b, g).
// -------------------------------------------------------------------------
__global__ __launch_bounds__(256) void gn_kernel(
    const float* __restrict__ x,
    const float* __restrict__ gamma,
    const float* __restrict__ beta,
    float* __restrict__ xn)
{
    const int b = blockIdx.x >> 5;
    const int g = blockIdx.x & 31;
    const size_t base = ((size_t)b * C_DIM + (size_t)g * CPG) * N_SP;
    const float* xp = x + base;
    float* xnp = xn + base;
    const int tid = threadIdx.x;
    const int tot = CPG * N_SP;

    float sum = 0.f, sumsq = 0.f;
    for (int idx = tid; idx < tot; idx += 256) {
        float v = xp[idx];
        sum += v;
        sumsq += v * v;
    }
    #pragma unroll
    for (int off = 32; off; off >>= 1) {
        sum   += __shfl_xor(sum, off);
        sumsq += __shfl_xor(sumsq, off);
    }
    __shared__ float red[2][4];
    const int w = tid >> 6;
    if ((tid & 63) == 0) { red[0][w] = sum; red[1][w] = sumsq; }
    __syncthreads();
    sum   = red[0][0] + red[0][1] + red[0][2] + red[0][3];
    sumsq = red[1][0] + red[1][1] + red[1][2] + red[1][3];

    const float inv_n = 1.0f / (float)tot;
    const float mean = sum * inv_n;
    const float var  = sumsq * inv_n - mean * mean;
    const float rstd = rsqrtf(var + 1e-5f);

    for (int idx = tid; idx < tot; idx += 256) {
        const int c = g * CPG + idx / N_SP;
        xnp[idx] = (xp[idx] - mean) * rstd * gamma[c] + beta[c];
    }
}

// -------------------------------------------------------------------------
// fp32 GEMM: acc[o][n] = bias[o] + sum_c W[o,c]*X[b,c,n]
// mode 0: Y[b,o,n] = acc (+resid)
// mode 1: bfout[(b*8+h)*N + n][DPAD] at col d = acc*scale (bf16, transposed)
// mode 2: bfout[(b*8+h)*VPAD + d][N] at col n = acc       (bf16, d-major)
// -------------------------------------------------------------------------
__global__ __launch_bounds__(256) void gemm_kernel(
    const float* __restrict__ W,
    const float* __restrict__ bias,
    const float* __restrict__ X,
    float* __restrict__ Y,
    const float* __restrict__ resid,
    __bf16* __restrict__ bfout,
    int mode, float scale)
{
    const int b  = blockIdx.z;
    const int n0 = blockIdx.x * 64;
    const int o0 = blockIdx.y * 64;

    __shared__ float Ws[16][65];
    __shared__ float Xs[16][65];

    const int tid = threadIdx.x;
    const int tx = tid & 15;
    const int ty = tid >> 4;
    const size_t xbase = (size_t)b * C_DIM * N_SP;

    float acc[4][4];
    #pragma unroll
    for (int i = 0; i < 4; ++i)
        #pragma unroll
        for (int j = 0; j < 4; ++j) acc[i][j] = 0.f;

    for (int k0 = 0; k0 < C_DIM; k0 += 16) {
        #pragma unroll
        for (int i = 0; i < 4; ++i) {
            const int idx = tid + i * 256;
            const int kk = idx & 15;
            const int oo = idx >> 4;
            Ws[kk][oo] = W[(size_t)(o0 + oo) * C_DIM + (k0 + kk)];
        }
        #pragma unroll
        for (int i = 0; i < 4; ++i) {
            const int idx = tid + i * 256;
            const int kk = idx >> 6;
            const int nn = idx & 63;
            Xs[kk][nn] = X[xbase + (size_t)(k0 + kk) * N_SP + (n0 + nn)];
        }
        __syncthreads();
        #pragma unroll
        for (int k = 0; k < 16; ++k) {
            float wv[4], xv[4];
            #pragma unroll
            for (int i = 0; i < 4; ++i) wv[i] = Ws[k][ty * 4 + i];
            #pragma unroll
            for (int j = 0; j < 4; ++j) xv[j] = Xs[k][tx * 4 + j];
            #pragma unroll
            for (int i = 0; i < 4; ++i)
                #pragma unroll
                for (int j = 0; j < 4; ++j)
                    acc[i][j] += wv[i] * xv[j];
        }
        __syncthreads();
    }

    #pragma unroll
    for (int i = 0; i < 4; ++i) {
        const int o = o0 + ty * 4 + i;
        const float bo_ = bias[o];
        if (mode == 0) {
            #pragma unroll
            for (int j = 0; j < 4; ++j) {
                const int n = n0 + tx * 4 + j;
                const size_t oidx = xbase + (size_t)o * N_SP + n;
                float r = resid ? resid[oidx] : 0.f;
                Y[oidx] = acc[i][j] + bo_ + r;
            }
        } else {
            const int h = o / DHEAD;
            const int d = o - h * DHEAD;
            const int bh = b * NHEADS + h;
            #pragma unroll
            for (int j = 0; j < 4; ++j) {
                const int n = n0 + tx * 4 + j;
                const float v = (acc[i][j] + bo_) * scale;
                if (mode == 1) {
                    bfout[((size_t)bh * N_SP + n) * DPAD + d] = (__bf16)v;
                } else {
                    bfout[((size_t)bh * VPAD + d) * N_SP + n] = (__bf16)v;
                }
            }
        }
    }
}

// -------------------------------------------------------------------------
// Flash attention, MFMA 16x16x32 bf16. One wave per 16-row Q strip.
// Qt,Kt: [bh][N_SP][DPAD] bf16 (pad zeroed; Qt pre-scaled by 1/sqrt(40))
// Vb:    [bh][VPAD][N_SP] bf16 (pad rows zeroed)
// A-frag: lane l -> row (l&15), k = 8*(l>>4)+e.  B-frag: col (l&15), k = 8*(l>>4)+e.
// C/D:    lane l, reg r -> row (l>>4)*4+r, col (l&15).
// -------------------------------------------------------------------------
__global__ __launch_bounds__(256) void attn_mfma(
    const __bf16* __restrict__ Qt,
    const __bf16* __restrict__ Kt,
    const __bf16* __restrict__ Vb,
    float* __restrict__ att)
{
    const int bh   = blockIdx.y;
    const int b    = bh >> 3;
    const int h    = bh & 7;
    const int wave = threadIdx.x >> 6;
    const int lane = threadIdx.x & 63;
    const int lrow = lane & 15;
    const int lk   = lane >> 4;          // 0..3
    const int i0   = (blockIdx.x * 4 + wave) * 16;

    const __bf16* Qp = Qt + ((size_t)bh * N_SP + i0) * DPAD;
    const __bf16* Kp = Kt + (size_t)bh * N_SP * DPAD;
    const __bf16* Vp = Vb + (size_t)bh * VPAD * N_SP;

    // Q fragments (two K=32 steps over d=0..63)
    bf16x8 qa0 = *(const bf16x8*)(Qp + (size_t)lrow * DPAD + lk * 8);
    bf16x8 qa1 = *(const bf16x8*)(Qp + (size_t)lrow * DPAD + 32 + lk * 8);

    __shared__ __align__(16) __bf16 plds_all[4][16][40];
    __bf16 (*plds)[40] = plds_all[wave];

    f32x4 O0 = {0.f, 0.f, 0.f, 0.f};
    f32x4 O1 = {0.f, 0.f, 0.f, 0.f};
    f32x4 O2 = {0.f, 0.f, 0.f, 0.f};
    float m[4]    = {-1e30f, -1e30f, -1e30f, -1e30f};
    float lsum[4] = {0.f, 0.f, 0.f, 0.f};

    for (int j0 = 0; j0 < N_SP; j0 += 32) {
        // ---- issue all global loads for this tile up front ----
        const __bf16* kb = Kp + (size_t)(j0 + lrow) * DPAD + lk * 8;
        bf16x8 kb00 = *(const bf16x8*)(kb);
        bf16x8 kb01 = *(const bf16x8*)(kb + 32);
        bf16x8 kb10 = *(const bf16x8*)(kb + 16 * DPAD);
        bf16x8 kb11 = *(const bf16x8*)(kb + 16 * DPAD + 32);
        const __bf16* vb = Vp + (size_t)lrow * N_SP + j0 + lk * 8;
        bf16x8 v0 = *(const bf16x8*)(vb);
        bf16x8 v1 = *(const bf16x8*)(vb + (size_t)16 * N_SP);
        bf16x8 v2 = *(const bf16x8*)(vb + (size_t)32 * N_SP);

        // ---- S = Q K^T (two 16x16 col tiles) ----
        f32x4 S0 = {0.f, 0.f, 0.f, 0.f};
        f32x4 S1 = {0.f, 0.f, 0.f, 0.f};
        S0 = MFMA16(qa0, kb00, S0);
        S0 = MFMA16(qa1, kb01, S0);
        S1 = MFMA16(qa0, kb10, S1);
        S1 = MFMA16(qa1, kb11, S1);

        // ---- online softmax (stats per reg r <-> row lk*4+r) ----
        float P0[4], P1[4];
        #pragma unroll
        for (int r = 0; r < 4; ++r) {
            float rmax = fmaxf(S0[r], S1[r]);
            #pragma unroll
            for (int off = 1; off < 16; off <<= 1)
                rmax = fmaxf(rmax, __shfl_xor(rmax, off));
            const float mn = fmaxf(m[r], rmax);
            const float f  = __expf(m[r] - mn);
            P0[r] = __expf(S0[r] - mn);
            P1[r] = __expf(S1[r] - mn);
            float rsum = P0[r] + P1[r];
            #pragma unroll
            for (int off = 1; off < 16; off <<= 1)
                rsum += __shfl_xor(rsum, off);
            lsum[r] = lsum[r] * f + rsum;
            m[r] = mn;
            O0[r] *= f; O1[r] *= f; O2[r] *= f;
        }

        // ---- P -> LDS (bf16), reload as PV A-fragment ----
        #pragma unroll
        for (int r = 0; r < 4; ++r) {
            plds[lk * 4 + r][lrow]      = (__bf16)P0[r];
            plds[lk * 4 + r][16 + lrow] = (__bf16)P1[r];
        }
        bf16x8 pa = *(const bf16x8*)(&plds[lrow][lk * 8]);

        // ---- O += P V ----
        O0 = MFMA16(pa, v0, O0);
        O1 = MFMA16(pa, v1, O1);
        O2 = MFMA16(pa, v2, O2);
    }

    // ---- epilogue: divide by lsum, store f32 att[b][c][n] ----
    float inv[4];
    #pragma unroll
    for (int r = 0; r < 4; ++r) inv[r] = 1.0f / lsum[r];

    const size_t abase = ((size_t)b * C_DIM + (size_t)h * DHEAD) * N_SP;
    #pragma unroll
    for (int r = 0; r < 4; ++r) {
        const int n = i0 + lk * 4 + r;
        att[abase + (size_t)(lrow) * N_SP + n]      = O0[r] * inv[r];
        att[abase + (size_t)(16 + lrow) * N_SP + n] = O1[r] * inv[r];
        if (lrow < 8)
            att[abase + (size_t)(32 + lrow) * N_SP + n] = O2[r] * inv[r];
    }
}

// -------------------------------------------------------------------------
extern "C" void kernel_launch(void* const* d_in, const int* in_sizes, int n_in,
                              void* d_out, int out_size, void* d_ws, size_t ws_size,
                              hipStream_t stream) {
    const float* x     = (const float*)d_in[0];
    const float* gamma = (const float*)d_in[1];
    const float* beta  = (const float*)d_in[2];
    const float* Wq    = (const float*)d_in[3];
    const float* bq    = (const float*)d_in[4];
    const float* Wk    = (const float*)d_in[5];
    const float* bk    = (const float*)d_in[6];
    const float* Wv    = (const float*)d_in[7];
    const float* bv    = (const float*)d_in[8];
    const float* Wo    = (const float*)d_in[9];
    const float* bo    = (const float*)d_in[10];

    float* out = (float*)d_out;
    float* ws  = (float*)d_ws;

    const size_t S = (size_t)BATCH * C_DIM * N_SP;   // 1,474,560 floats
    float* xn  = ws;
    float* att = ws + S;
    __bf16* Qt = (__bf16*)(ws + 2 * S);
    __bf16* Kt = Qt + (size_t)BATCH * NHEADS * N_SP * DPAD;
    __bf16* Vb = Kt + (size_t)BATCH * NHEADS * N_SP * DPAD;
    const size_t bf_elems = (size_t)BATCH * NHEADS * N_SP * DPAD * 2
                          + (size_t)BATCH * NHEADS * VPAD * N_SP;

    // zero bf16 buffers (covers d-padding that the GEMM epilogues never touch)
    hipMemsetAsync(Qt, 0, bf_elems * sizeof(__bf16), stream);

    gn_kernel<<<BATCH * GROUPS, 256, 0, stream>>>(x, gamma, beta, xn);

    dim3 ggrid(N_SP / 64, C_DIM / 64, BATCH);
    const float qscale = 0.15811388300841897f;  // 1/sqrt(40)
    gemm_kernel<<<ggrid, 256, 0, stream>>>(Wq, bq, xn, nullptr, nullptr, Qt, 1, qscale);
    gemm_kernel<<<ggrid, 256, 0, stream>>>(Wk, bk, xn, nullptr, nullptr, Kt, 1, 1.0f);
    gemm_kernel<<<ggrid, 256, 0, stream>>>(Wv, bv, xn, nullptr, nullptr, Vb, 2, 1.0f);

    attn_mfma<<<dim3(N_SP / 64, BATCH * NHEADS), 256, 0, stream>>>(Qt, Kt, Vb, att);

    gemm_kernel<<<ggrid, 256, 0, stream>>>(Wo, bo, att, out, x, nullptr, 0, 1.0f);
}

// Round 3
// 265.684 us; speedup vs baseline: 40.0314x; 1.3759x over previous
//
#include <hip/hip_runtime.h>
#include <hip/hip_bf16.h>

#define C_DIM   320
#define N_SP    2304      // 48*48
#define NHEADS  8
#define DHEAD   40
#define GROUPS  32
#define CPG     10
#define BATCH   2
#define DPAD    64        // d padded for K=32 MFMA steps
#define VPAD    48        // v rows padded to 3x16

typedef __bf16 bf16x8 __attribute__((ext_vector_type(8)));
typedef __bf16 bf16x4 __attribute__((ext_vector_type(4)));
typedef __bf16 bf16x2 __attribute__((ext_vector_type(2)));
typedef float  f32x4  __attribute__((ext_vector_type(4)));

#define MFMA16(a, b, c) __builtin_amdgcn_mfma_f32_16x16x32_bf16((a), (b), (c), 0, 0, 0)

// -------------------------------------------------------------------------
// GroupNorm: one block per (b, g). Writes xn_t [B][N][C] bf16 (n-major).
// -------------------------------------------------------------------------
__global__ __launch_bounds__(256) void gn_kernel(
    const float* __restrict__ x,
    const float* __restrict__ gamma,
    const float* __restrict__ beta,
    __bf16* __restrict__ xn_t)
{
    const int b = blockIdx.x >> 5;
    const int g = blockIdx.x & 31;
    const int c0 = g * CPG;
    const float* xp = x + ((size_t)b * C_DIM + c0) * N_SP;
    const int tid = threadIdx.x;
    const int tot = CPG * N_SP;

    float sum = 0.f, sumsq = 0.f;
    for (int idx = tid; idx < tot; idx += 256) {
        float v = xp[idx];
        sum += v;
        sumsq += v * v;
    }
    #pragma unroll
    for (int off = 32; off; off >>= 1) {
        sum   += __shfl_xor(sum, off);
        sumsq += __shfl_xor(sumsq, off);
    }
    __shared__ float red[2][4];
    const int w = tid >> 6;
    if ((tid & 63) == 0) { red[0][w] = sum; red[1][w] = sumsq; }
    __syncthreads();
    sum   = red[0][0] + red[0][1] + red[0][2] + red[0][3];
    sumsq = red[1][0] + red[1][1] + red[1][2] + red[1][3];

    const float inv_n = 1.0f / (float)tot;
    const float mean = sum * inv_n;
    const float var  = sumsq * inv_n - mean * mean;
    const float rstd = rsqrtf(var + 1e-5f);

    float ga[CPG], be[CPG];
    #pragma unroll
    for (int c = 0; c < CPG; ++c) {
        ga[c] = gamma[c0 + c] * rstd;
        be[c] = beta[c0 + c] - mean * ga[c];
    }

    // pass 2: normalize + write transposed bf16 (20B per n-row chunk)
    for (int n = tid; n < N_SP; n += 256) {
        __bf16* dst = xn_t + ((size_t)b * N_SP + n) * C_DIM + c0;
        #pragma unroll
        for (int j = 0; j < CPG / 2; ++j) {
            const float v0 = xp[(size_t)(2 * j) * N_SP + n]     * ga[2 * j]     + be[2 * j];
            const float v1 = xp[(size_t)(2 * j + 1) * N_SP + n] * ga[2 * j + 1] + be[2 * j + 1];
            bf16x2 t; t[0] = (__bf16)v0; t[1] = (__bf16)v1;
            *(bf16x2*)(dst + 2 * j) = t;
        }
    }
}

// -------------------------------------------------------------------------
// Shared GEMM core: per wave computes 32x32 of Y = W(fp32) * Xt^T(bf16).
// acc[am][bn] row = 4*lk+r (o-offset), col = lr (n-offset).
// -------------------------------------------------------------------------
__device__ __forceinline__ void gemm_core(
    const float* __restrict__ W, const __bf16* __restrict__ Xb,
    int o0w, int n0w, int lr, int lk, f32x4 acc[2][2])
{
    const float*  wp0 = W + (size_t)(o0w + lr) * C_DIM + lk * 8;
    const float*  wp1 = wp0 + 16 * C_DIM;
    const __bf16* xp0 = Xb + (size_t)(n0w + lr) * C_DIM + lk * 8;
    const __bf16* xp1 = xp0 + 16 * C_DIM;

    for (int k0 = 0; k0 < C_DIM; k0 += 32) {
        f32x4 wa0 = *(const f32x4*)(wp0 + k0);
        f32x4 wa1 = *(const f32x4*)(wp0 + k0 + 4);
        f32x4 wb0 = *(const f32x4*)(wp1 + k0);
        f32x4 wb1 = *(const f32x4*)(wp1 + k0 + 4);
        bf16x8 a0, a1;
        #pragma unroll
        for (int e = 0; e < 4; ++e) {
            a0[e] = (__bf16)wa0[e]; a0[4 + e] = (__bf16)wa1[e];
            a1[e] = (__bf16)wb0[e]; a1[4 + e] = (__bf16)wb1[e];
        }
        bf16x8 b0 = *(const bf16x8*)(xp0 + k0);
        bf16x8 b1 = *(const bf16x8*)(xp1 + k0);
        acc[0][0] = MFMA16(a0, b0, acc[0][0]);
        acc[0][1] = MFMA16(a0, b1, acc[0][1]);
        acc[1][0] = MFMA16(a1, b0, acc[1][0]);
        acc[1][1] = MFMA16(a1, b1, acc[1][1]);
    }
}

// -------------------------------------------------------------------------
// Fused QKV projection. grid (36, 5, 6): z = b*3 + which.
// Q/K -> [bh][n][DPAD] bf16 (Q pre-scaled); V -> [bh][VPAD][N] bf16.
// -------------------------------------------------------------------------
__global__ __launch_bounds__(256) void gemm_qkv(
    const float* __restrict__ Wq, const float* __restrict__ Wk, const float* __restrict__ Wv,
    const float* __restrict__ bq, const float* __restrict__ bk, const float* __restrict__ bv,
    const __bf16* __restrict__ Xt,
    __bf16* __restrict__ Qt, __bf16* __restrict__ Kt, __bf16* __restrict__ Vb)
{
    const int z = blockIdx.z;
    const int b = z / 3;
    const int which = z - 3 * b;
    const float* W    = (which == 0) ? Wq : (which == 1) ? Wk : Wv;
    const float* bias = (which == 0) ? bq : (which == 1) ? bk : bv;
    const float scale = (which == 0) ? 0.15811388300841897f : 1.0f;

    const int n0 = blockIdx.x * 64, o0 = blockIdx.y * 64;
    const int tid = threadIdx.x, wave = tid >> 6, lane = tid & 63;
    const int lr = lane & 15, lk = lane >> 4;
    const int wm = wave >> 1, wn = wave & 1;

    f32x4 acc[2][2] = {};
    gemm_core(W, Xt + (size_t)b * N_SP * C_DIM, o0 + wm * 32, n0 + wn * 32, lr, lk, acc);

    #pragma unroll
    for (int am = 0; am < 2; ++am) {
        #pragma unroll
        for (int r = 0; r < 4; ++r) {
            const int o = o0 + wm * 32 + am * 16 + 4 * lk + r;
            const float bv_ = bias[o];
            const int h = o / DHEAD, d = o - h * DHEAD;
            const int bh = b * NHEADS + h;
            #pragma unroll
            for (int bn = 0; bn < 2; ++bn) {
                const int n = n0 + wn * 32 + bn * 16 + lr;
                const float v = (acc[am][bn][r] + bv_) * scale;
                if (which < 2) {
                    __bf16* dst = (which == 0) ? Qt : Kt;
                    dst[((size_t)bh * N_SP + n) * DPAD + d] = (__bf16)v;
                } else {
                    Vb[((size_t)bh * VPAD + d) * N_SP + n] = (__bf16)v;
                }
            }
        }
    }
}

// -------------------------------------------------------------------------
// Output projection: out[b][o][n] = Wo * att_t^T + bo + x  (fp32 out)
// -------------------------------------------------------------------------
__global__ __launch_bounds__(256) void gemm_out(
    const float* __restrict__ Wo, const float* __restrict__ bo,
    const __bf16* __restrict__ att_t,
    float* __restrict__ Y, const float* __restrict__ resid)
{
    const int b = blockIdx.z;
    const int n0 = blockIdx.x * 64, o0 = blockIdx.y * 64;
    const int tid = threadIdx.x, wave = tid >> 6, lane = tid & 63;
    const int lr = lane & 15, lk = lane >> 4;
    const int wm = wave >> 1, wn = wave & 1;

    f32x4 acc[2][2] = {};
    gemm_core(Wo, att_t + (size_t)b * N_SP * C_DIM, o0 + wm * 32, n0 + wn * 32, lr, lk, acc);

    #pragma unroll
    for (int am = 0; am < 2; ++am) {
        #pragma unroll
        for (int r = 0; r < 4; ++r) {
            const int o = o0 + wm * 32 + am * 16 + 4 * lk + r;
            const float bv_ = bo[o];
            #pragma unroll
            for (int bn = 0; bn < 2; ++bn) {
                const int n = n0 + wn * 32 + bn * 16 + lr;
                const size_t idx = ((size_t)b * C_DIM + o) * N_SP + n;
                Y[idx] = acc[am][bn][r] + bv_ + resid[idx];
            }
        }
    }
}

// -------------------------------------------------------------------------
// Flash attention, swapped operands: S^T = mfma(K, Q) so each lane owns one
// q-column; softmax stats are per-lane scalars + 2 shuffles per reduction.
// O^T = mfma(V^T, P^T). Writes att_t [B][N][320] bf16.
// -------------------------------------------------------------------------
__global__ __launch_bounds__(256) void attn_mfma(
    const __bf16* __restrict__ Qt,
    const __bf16* __restrict__ Kt,
    const __bf16* __restrict__ Vb,
    __bf16* __restrict__ att_t)
{
    const int bh   = blockIdx.y;
    const int b    = bh >> 3;
    const int h    = bh & 7;
    const int wave = threadIdx.x >> 6;
    const int lane = threadIdx.x & 63;
    const int lr   = lane & 15;
    const int lk   = lane >> 4;
    const int i0   = (blockIdx.x * 4 + wave) * 16;

    // Q as B-operand: col q = lr, k(=d) = 8*lk+e
    const __bf16* Qp = Qt + ((size_t)bh * N_SP + i0 + lr) * DPAD + lk * 8;
    const bf16x8 qb0 = *(const bf16x8*)(Qp);
    const bf16x8 qb1 = *(const bf16x8*)(Qp + 32);

    const __bf16* Kbase = Kt + (size_t)bh * N_SP * DPAD;
    const __bf16* Vbase = Vb + ((size_t)bh * VPAD + lr) * N_SP;  // row d = lr

    __shared__ __align__(16) __bf16 plds_all[4][16][40];  // [q][k] per wave
    __bf16 (*plds)[40] = plds_all[wave];

    f32x4 O0 = {}, O1 = {}, O2 = {};   // O^T: row d = 16*t + 4*lk + r, col q = lr
    float m = -1e30f, lsum = 0.f;

    for (int j0 = 0; j0 < N_SP; j0 += 32) {
        // K as A-operand: row k-local = lr, k(=d) = 8*lk+e
        const __bf16* kp = Kbase + (size_t)(j0 + lr) * DPAD + lk * 8;
        const bf16x8 kb00 = *(const bf16x8*)(kp);
        const bf16x8 kb01 = *(const bf16x8*)(kp + 32);
        const bf16x8 kb10 = *(const bf16x8*)(kp + 16 * DPAD);
        const bf16x8 kb11 = *(const bf16x8*)(kp + 16 * DPAD + 32);
        // V^T as A-operand: row d = lr (+16t), k = j-local = 8*lk+e
        const bf16x8 va0 = *(const bf16x8*)(Vbase + j0 + lk * 8);
        const bf16x8 va1 = *(const bf16x8*)(Vbase + (size_t)16 * N_SP + j0 + lk * 8);
        const bf16x8 va2 = *(const bf16x8*)(Vbase + (size_t)32 * N_SP + j0 + lk * 8);

        f32x4 S0 = {}, S1 = {};
        S0 = MFMA16(kb00, qb0, S0);   // S^T[k=4lk+r][q=lr], k 0..15
        S0 = MFMA16(kb01, qb1, S0);
        S1 = MFMA16(kb10, qb0, S1);   // k 16..31
        S1 = MFMA16(kb11, qb1, S1);

        // ---- online softmax: per-lane scalars, 2+2 shuffles total ----
        float tmax = fmaxf(fmaxf(fmaxf(S0[0], S0[1]), fmaxf(S0[2], S0[3])),
                           fmaxf(fmaxf(S1[0], S1[1]), fmaxf(S1[2], S1[3])));
        tmax = fmaxf(tmax, __shfl_xor(tmax, 16));
        tmax = fmaxf(tmax, __shfl_xor(tmax, 32));
        const float mn = fmaxf(m, tmax);
        const float f  = __expf(m - mn);
        float p0[4], p1[4];
        float rsum = 0.f;
        #pragma unroll
        for (int r = 0; r < 4; ++r) {
            p0[r] = __expf(S0[r] - mn);
            p1[r] = __expf(S1[r] - mn);
            rsum += p0[r] + p1[r];
        }
        rsum += __shfl_xor(rsum, 16);
        rsum += __shfl_xor(rsum, 32);
        lsum = lsum * f + rsum;
        m = mn;
        #pragma unroll
        for (int r = 0; r < 4; ++r) { O0[r] *= f; O1[r] *= f; O2[r] *= f; }

        // ---- P^T -> LDS [q][k], reload as PV B-fragment ----
        bf16x4 w0, w1;
        #pragma unroll
        for (int r = 0; r < 4; ++r) { w0[r] = (__bf16)p0[r]; w1[r] = (__bf16)p1[r]; }
        *(bf16x4*)(&plds[lr][4 * lk])      = w0;
        *(bf16x4*)(&plds[lr][16 + 4 * lk]) = w1;
        const bf16x8 pb = *(const bf16x8*)(&plds[lr][lk * 8]);

        O0 = MFMA16(va0, pb, O0);
        O1 = MFMA16(va1, pb, O1);
        O2 = MFMA16(va2, pb, O2);
    }

    // ---- epilogue: O^T / lsum -> att_t [B][N][320] bf16 ----
    const float inv = 1.0f / lsum;
    __bf16* op = att_t + ((size_t)b * N_SP + i0 + lr) * C_DIM + h * DHEAD;
    bf16x4 o0v, o1v, o2v;
    #pragma unroll
    for (int r = 0; r < 4; ++r) {
        o0v[r] = (__bf16)(O0[r] * inv);
        o1v[r] = (__bf16)(O1[r] * inv);
        o2v[r] = (__bf16)(O2[r] * inv);
    }
    *(bf16x4*)(op + 4 * lk)      = o0v;
    *(bf16x4*)(op + 16 + 4 * lk) = o1v;
    if (lk < 2)
        *(bf16x4*)(op + 32 + 4 * lk) = o2v;   // d 32..39 only (skip pad)
}

// -------------------------------------------------------------------------
extern "C" void kernel_launch(void* const* d_in, const int* in_sizes, int n_in,
                              void* d_out, int out_size, void* d_ws, size_t ws_size,
                              hipStream_t stream) {
    const float* x     = (const float*)d_in[0];
    const float* gamma = (const float*)d_in[1];
    const float* beta  = (const float*)d_in[2];
    const float* Wq    = (const float*)d_in[3];
    const float* bq    = (const float*)d_in[4];
    const float* Wk    = (const float*)d_in[5];
    const float* bk    = (const float*)d_in[6];
    const float* Wv    = (const float*)d_in[7];
    const float* bv    = (const float*)d_in[8];
    const float* Wo    = (const float*)d_in[9];
    const float* bo    = (const float*)d_in[10];

    float* out = (float*)d_out;

    const size_t S_NC  = (size_t)BATCH * N_SP * C_DIM;          // 1,474,560
    const size_t S_QK  = (size_t)BATCH * NHEADS * N_SP * DPAD;  // 2,359,296
    const size_t S_V   = (size_t)BATCH * NHEADS * VPAD * N_SP;  // 1,769,472

    __bf16* xn_t  = (__bf16*)d_ws;
    __bf16* Qt    = xn_t + S_NC;
    __bf16* Kt    = Qt + S_QK;
    __bf16* Vb    = Kt + S_QK;
    __bf16* att_t = Vb + S_V;

    // zero Q/K/V buffers (covers d-padding the GEMM epilogues never touch)
    hipMemsetAsync(Qt, 0, (2 * S_QK + S_V) * sizeof(__bf16), stream);

    gn_kernel<<<BATCH * GROUPS, 256, 0, stream>>>(x, gamma, beta, xn_t);

    gemm_qkv<<<dim3(N_SP / 64, C_DIM / 64, 3 * BATCH), 256, 0, stream>>>(
        Wq, Wk, Wv, bq, bk, bv, xn_t, Qt, Kt, Vb);

    attn_mfma<<<dim3(N_SP / 64, BATCH * NHEADS), 256, 0, stream>>>(Qt, Kt, Vb, att_t);

    gemm_out<<<dim3(N_SP / 64, C_DIM / 64, BATCH), 256, 0, stream>>>(
        Wo, bo, att_t, out, x);
}

// Round 4
// 152.276 us; speedup vs baseline: 69.8451x; 1.7448x over previous
//
#include <hip/hip_runtime.h>
#include <hip/hip_bf16.h>

#define C_DIM   320
#define N_SP    2304      // 48*48
#define NHEADS  8
#define DHEAD   40
#define GROUPS  32
#define CPG     10
#define BATCH   2
#define DPAD    64        // d padded for K=32 MFMA steps
#define VPAD    48        // v rows padded to 3x16

typedef __bf16 bf16x8 __attribute__((ext_vector_type(8)));
typedef __bf16 bf16x4 __attribute__((ext_vector_type(4)));
typedef __bf16 bf16x2 __attribute__((ext_vector_type(2)));
typedef float  f32x4  __attribute__((ext_vector_type(4)));

typedef const __attribute__((address_space(1))) void* gas_ptr;
typedef __attribute__((address_space(3))) void* las_ptr;

#define MFMA16(a, b, c) __builtin_amdgcn_mfma_f32_16x16x32_bf16((a), (b), (c), 0, 0, 0)

// -------------------------------------------------------------------------
// GroupNorm: one block per (b, g). Writes xn_t [B][N][C] bf16 (n-major).
// -------------------------------------------------------------------------
__global__ __launch_bounds__(256) void gn_kernel(
    const float* __restrict__ x,
    const float* __restrict__ gamma,
    const float* __restrict__ beta,
    __bf16* __restrict__ xn_t)
{
    const int b = blockIdx.x >> 5;
    const int g = blockIdx.x & 31;
    const int c0 = g * CPG;
    const float* xp = x + ((size_t)b * C_DIM + c0) * N_SP;
    const int tid = threadIdx.x;
    const int tot = CPG * N_SP;

    float sum = 0.f, sumsq = 0.f;
    for (int idx = tid; idx < tot; idx += 256) {
        float v = xp[idx];
        sum += v;
        sumsq += v * v;
    }
    #pragma unroll
    for (int off = 32; off; off >>= 1) {
        sum   += __shfl_xor(sum, off);
        sumsq += __shfl_xor(sumsq, off);
    }
    __shared__ float red[2][4];
    const int w = tid >> 6;
    if ((tid & 63) == 0) { red[0][w] = sum; red[1][w] = sumsq; }
    __syncthreads();
    sum   = red[0][0] + red[0][1] + red[0][2] + red[0][3];
    sumsq = red[1][0] + red[1][1] + red[1][2] + red[1][3];

    const float inv_n = 1.0f / (float)tot;
    const float mean = sum * inv_n;
    const float var  = sumsq * inv_n - mean * mean;
    const float rstd = rsqrtf(var + 1e-5f);

    float ga[CPG], be[CPG];
    #pragma unroll
    for (int c = 0; c < CPG; ++c) {
        ga[c] = gamma[c0 + c] * rstd;
        be[c] = beta[c0 + c] - mean * ga[c];
    }

    for (int n = tid; n < N_SP; n += 256) {
        __bf16* dst = xn_t + ((size_t)b * N_SP + n) * C_DIM + c0;
        #pragma unroll
        for (int j = 0; j < CPG / 2; ++j) {
            const float v0 = xp[(size_t)(2 * j) * N_SP + n]     * ga[2 * j]     + be[2 * j];
            const float v1 = xp[(size_t)(2 * j + 1) * N_SP + n] * ga[2 * j + 1] + be[2 * j + 1];
            bf16x2 t; t[0] = (__bf16)v0; t[1] = (__bf16)v1;
            *(bf16x2*)(dst + 2 * j) = t;
        }
    }
}

// -------------------------------------------------------------------------
// Shared GEMM core: per wave computes 32x32 of Y = W(fp32) * Xt^T(bf16).
// -------------------------------------------------------------------------
__device__ __forceinline__ void gemm_core(
    const float* __restrict__ W, const __bf16* __restrict__ Xb,
    int o0w, int n0w, int lr, int lk, f32x4 acc[2][2])
{
    const float*  wp0 = W + (size_t)(o0w + lr) * C_DIM + lk * 8;
    const float*  wp1 = wp0 + 16 * C_DIM;
    const __bf16* xp0 = Xb + (size_t)(n0w + lr) * C_DIM + lk * 8;
    const __bf16* xp1 = xp0 + 16 * C_DIM;

    for (int k0 = 0; k0 < C_DIM; k0 += 32) {
        f32x4 wa0 = *(const f32x4*)(wp0 + k0);
        f32x4 wa1 = *(const f32x4*)(wp0 + k0 + 4);
        f32x4 wb0 = *(const f32x4*)(wp1 + k0);
        f32x4 wb1 = *(const f32x4*)(wp1 + k0 + 4);
        bf16x8 a0, a1;
        #pragma unroll
        for (int e = 0; e < 4; ++e) {
            a0[e] = (__bf16)wa0[e]; a0[4 + e] = (__bf16)wa1[e];
            a1[e] = (__bf16)wb0[e]; a1[4 + e] = (__bf16)wb1[e];
        }
        bf16x8 b0 = *(const bf16x8*)(xp0 + k0);
        bf16x8 b1 = *(const bf16x8*)(xp1 + k0);
        acc[0][0] = MFMA16(a0, b0, acc[0][0]);
        acc[0][1] = MFMA16(a0, b1, acc[0][1]);
        acc[1][0] = MFMA16(a1, b0, acc[1][0]);
        acc[1][1] = MFMA16(a1, b1, acc[1][1]);
    }
}

// -------------------------------------------------------------------------
// Fused QKV projection. grid (36, 5, 6): z = b*3 + which.
// -------------------------------------------------------------------------
__global__ __launch_bounds__(256) void gemm_qkv(
    const float* __restrict__ Wq, const float* __restrict__ Wk, const float* __restrict__ Wv,
    const float* __restrict__ bq, const float* __restrict__ bk, const float* __restrict__ bv,
    const __bf16* __restrict__ Xt,
    __bf16* __restrict__ Qt, __bf16* __restrict__ Kt, __bf16* __restrict__ Vb)
{
    const int z = blockIdx.z;
    const int b = z / 3;
    const int which = z - 3 * b;
    const float* W    = (which == 0) ? Wq : (which == 1) ? Wk : Wv;
    const float* bias = (which == 0) ? bq : (which == 1) ? bk : bv;
    const float scale = (which == 0) ? 0.15811388300841897f : 1.0f;

    const int n0 = blockIdx.x * 64, o0 = blockIdx.y * 64;
    const int tid = threadIdx.x, wave = tid >> 6, lane = tid & 63;
    const int lr = lane & 15, lk = lane >> 4;
    const int wm = wave >> 1, wn = wave & 1;

    f32x4 acc[2][2] = {};
    gemm_core(W, Xt + (size_t)b * N_SP * C_DIM, o0 + wm * 32, n0 + wn * 32, lr, lk, acc);

    #pragma unroll
    for (int am = 0; am < 2; ++am) {
        #pragma unroll
        for (int r = 0; r < 4; ++r) {
            const int o = o0 + wm * 32 + am * 16 + 4 * lk + r;
            const float bv_ = bias[o];
            const int h = o / DHEAD, d = o - h * DHEAD;
            const int bh = b * NHEADS + h;
            #pragma unroll
            for (int bn = 0; bn < 2; ++bn) {
                const int n = n0 + wn * 32 + bn * 16 + lr;
                const float v = (acc[am][bn][r] + bv_) * scale;
                if (which < 2) {
                    __bf16* dst = (which == 0) ? Qt : Kt;
                    dst[((size_t)bh * N_SP + n) * DPAD + d] = (__bf16)v;
                } else {
                    Vb[((size_t)bh * VPAD + d) * N_SP + n] = (__bf16)v;
                }
            }
        }
    }
}

// -------------------------------------------------------------------------
// Output projection: out[b][o][n] = Wo * att_t^T + bo + x  (fp32 out)
// -------------------------------------------------------------------------
__global__ __launch_bounds__(256) void gemm_out(
    const float* __restrict__ Wo, const float* __restrict__ bo,
    const __bf16* __restrict__ att_t,
    float* __restrict__ Y, const float* __restrict__ resid)
{
    const int b = blockIdx.z;
    const int n0 = blockIdx.x * 64, o0 = blockIdx.y * 64;
    const int tid = threadIdx.x, wave = tid >> 6, lane = tid & 63;
    const int lr = lane & 15, lk = lane >> 4;
    const int wm = wave >> 1, wn = wave & 1;

    f32x4 acc[2][2] = {};
    gemm_core(Wo, att_t + (size_t)b * N_SP * C_DIM, o0 + wm * 32, n0 + wn * 32, lr, lk, acc);

    #pragma unroll
    for (int am = 0; am < 2; ++am) {
        #pragma unroll
        for (int r = 0; r < 4; ++r) {
            const int o = o0 + wm * 32 + am * 16 + 4 * lk + r;
            const float bv_ = bo[o];
            #pragma unroll
            for (int bn = 0; bn < 2; ++bn) {
                const int n = n0 + wn * 32 + bn * 16 + lr;
                const size_t idx = ((size_t)b * C_DIM + o) * N_SP + n;
                Y[idx] = acc[am][bn][r] + bv_ + resid[idx];
            }
        }
    }
}

// -------------------------------------------------------------------------
// Flash attention, block-cooperative KV staging.
// Block = 4 waves, 64 q rows; KV tiles of 64 keys double-buffered in LDS via
// global_load_lds with pre-swizzled sources (XOR ((row&7)<<4) swizzle).
// S^T = mfma(K, Q); P^T via per-wave swizzled LDS; O^T = mfma(V^T, P^T).
// -------------------------------------------------------------------------
__global__ __launch_bounds__(256) void attn_mfma(
    const __bf16* __restrict__ Qt,
    const __bf16* __restrict__ Kt,
    const __bf16* __restrict__ Vb,
    __bf16* __restrict__ att_t)
{
    __shared__ __align__(16) __bf16 Ks[2][64 * DPAD];   // 2 x 8KB
    __shared__ __align__(16) __bf16 Vs[2][VPAD * 64];   // 2 x 6KB
    __shared__ __align__(16) __bf16 Ps[4][16 * 64];     // per-wave P^T, 4 x 2KB

    const int bh = blockIdx.y, b = bh >> 3, h = bh & 7;
    const int tid = threadIdx.x, wave = tid >> 6, lane = tid & 63;
    const int lr = lane & 15, lk = lane >> 4;
    const int swz = (lr & 7) << 4;
    const int i0 = (blockIdx.x * 4 + wave) * 16;

    const char* Kg = (const char*)(Kt + (size_t)bh * N_SP * DPAD);
    const char* Vg = (const char*)(Vb + (size_t)bh * VPAD * N_SP);

    // Q fragments (held in registers for the whole kernel)
    const __bf16* Qp = Qt + ((size_t)bh * N_SP + i0 + lr) * DPAD + lk * 8;
    const bf16x8 qb0 = *(const bf16x8*)(Qp);
    const bf16x8 qb1 = *(const bf16x8*)(Qp + 32);

    f32x4 O[3] = {};
    float m = -1e30f, lsum = 0.f;

    // ---- staging: async global -> LDS, sources pre-swizzled ----
    auto stage = [&](int bufi, int t) {
        const int j0 = t * 64;
        // K tile: contiguous 8KB, 8 chunks of 1KB, 2 per wave
        #pragma unroll
        for (int i2 = 0; i2 < 2; ++i2) {
            const int chunk = wave * 2 + i2;
            const int L = chunk * 1024 + lane * 16;
            const int src = L ^ (((L >> 7) & 7) << 4);
            __builtin_amdgcn_global_load_lds(
                (gas_ptr)(Kg + (size_t)j0 * 128 + src),
                (las_ptr)((char*)Ks[bufi] + chunk * 1024),
                16, 0, 0);
        }
        // V^T tile: 48 rows x 128B, 6 chunks of 1KB (8 rows each)
        for (int i2 = wave; i2 < 6; i2 += 4) {
            const int row = i2 * 8 + (lane >> 3);
            const int csw = ((lane & 7) << 4) ^ ((row & 7) << 4);
            __builtin_amdgcn_global_load_lds(
                (gas_ptr)(Vg + ((size_t)row * N_SP + j0) * 2 + csw),
                (las_ptr)((char*)Vs[bufi] + i2 * 1024),
                16, 0, 0);
        }
    };

    stage(0, 0);
    __syncthreads();

    for (int t = 0; t < 36; ++t) {
        const int bufi = t & 1;
        if (t + 1 < 36) stage(bufi ^ 1, t + 1);   // prefetch next tile

        const char* ks = (const char*)Ks[bufi];
        const char* vs = (const char*)Vs[bufi];
        char* ps = (char*)Ps[wave];

        // ---- S^T = K · Q  (4 k-tiles of 16) ----
        f32x4 S[4];
        #pragma unroll
        for (int kt = 0; kt < 4; ++kt) {
            const int rowb = (kt * 16 + lr) * 128;
            const bf16x8 k0 = *(const bf16x8*)(ks + rowb + ((lk * 16) ^ swz));
            const bf16x8 k1 = *(const bf16x8*)(ks + rowb + ((64 + lk * 16) ^ swz));
            f32x4 z = {};
            z = MFMA16(k0, qb0, z);
            S[kt] = MFMA16(k1, qb1, z);
        }

        // ---- online softmax (per-lane scalars, 2+2 shuffles) ----
        float tmax = -1e30f;
        #pragma unroll
        for (int kt = 0; kt < 4; ++kt)
            #pragma unroll
            for (int r = 0; r < 4; ++r) tmax = fmaxf(tmax, S[kt][r]);
        tmax = fmaxf(tmax, __shfl_xor(tmax, 16));
        tmax = fmaxf(tmax, __shfl_xor(tmax, 32));
        const float mn = fmaxf(m, tmax);
        const float f  = __expf(m - mn);
        float rsum = 0.f;
        #pragma unroll
        for (int kt = 0; kt < 4; ++kt) {
            bf16x4 w;
            #pragma unroll
            for (int r = 0; r < 4; ++r) {
                const float p = __expf(S[kt][r] - mn);
                rsum += p;
                w[r] = (__bf16)p;
            }
            *(bf16x4*)(ps + lr * 128 + ((kt * 32 + lk * 8) ^ swz)) = w;
        }
        rsum += __shfl_xor(rsum, 16);
        rsum += __shfl_xor(rsum, 32);
        lsum = lsum * f + rsum;
        m = mn;
        #pragma unroll
        for (int dt = 0; dt < 3; ++dt)
            #pragma unroll
            for (int r = 0; r < 4; ++r) O[dt][r] *= f;

        // ---- O^T += V^T · P^T ----
        #pragma unroll
        for (int hh = 0; hh < 2; ++hh) {
            const bf16x8 pb = *(const bf16x8*)(ps + lr * 128 + ((hh * 64 + lk * 16) ^ swz));
            #pragma unroll
            for (int dt = 0; dt < 3; ++dt) {
                const bf16x8 va = *(const bf16x8*)(vs + (dt * 16 + lr) * 128 + ((hh * 64 + lk * 16) ^ swz));
                O[dt] = MFMA16(va, pb, O[dt]);
            }
        }

        __syncthreads();
    }

    // ---- epilogue: O^T / lsum -> att_t [B][N][320] bf16 ----
    const float inv = 1.0f / lsum;
    __bf16* op = att_t + ((size_t)b * N_SP + i0 + lr) * C_DIM + h * DHEAD;
    bf16x4 o0v, o1v, o2v;
    #pragma unroll
    for (int r = 0; r < 4; ++r) {
        o0v[r] = (__bf16)(O[0][r] * inv);
        o1v[r] = (__bf16)(O[1][r] * inv);
        o2v[r] = (__bf16)(O[2][r] * inv);
    }
    *(bf16x4*)(op + 4 * lk)      = o0v;
    *(bf16x4*)(op + 16 + 4 * lk) = o1v;
    if (lk < 2)
        *(bf16x4*)(op + 32 + 4 * lk) = o2v;   // d 32..39 only (skip pad)
}

// -------------------------------------------------------------------------
extern "C" void kernel_launch(void* const* d_in, const int* in_sizes, int n_in,
                              void* d_out, int out_size, void* d_ws, size_t ws_size,
                              hipStream_t stream) {
    const float* x     = (const float*)d_in[0];
    const float* gamma = (const float*)d_in[1];
    const float* beta  = (const float*)d_in[2];
    const float* Wq    = (const float*)d_in[3];
    const float* bq    = (const float*)d_in[4];
    const float* Wk    = (const float*)d_in[5];
    const float* bk    = (const float*)d_in[6];
    const float* Wv    = (const float*)d_in[7];
    const float* bv    = (const float*)d_in[8];
    const float* Wo    = (const float*)d_in[9];
    const float* bo    = (const float*)d_in[10];

    float* out = (float*)d_out;

    const size_t S_NC  = (size_t)BATCH * N_SP * C_DIM;          // 1,474,560
    const size_t S_QK  = (size_t)BATCH * NHEADS * N_SP * DPAD;  // 2,359,296
    const size_t S_V   = (size_t)BATCH * NHEADS * VPAD * N_SP;  // 1,769,472

    __bf16* xn_t  = (__bf16*)d_ws;
    __bf16* Qt    = xn_t + S_NC;
    __bf16* Kt    = Qt + S_QK;
    __bf16* Vb    = Kt + S_QK;
    __bf16* att_t = Vb + S_V;

    // zero Q/K/V buffers (covers d-padding the GEMM epilogues never touch)
    hipMemsetAsync(Qt, 0, (2 * S_QK + S_V) * sizeof(__bf16), stream);

    gn_kernel<<<BATCH * GROUPS, 256, 0, stream>>>(x, gamma, beta, xn_t);

    gemm_qkv<<<dim3(N_SP / 64, C_DIM / 64, 3 * BATCH), 256, 0, stream>>>(
        Wq, Wk, Wv, bq, bk, bv, xn_t, Qt, Kt, Vb);

    attn_mfma<<<dim3(N_SP / 64, BATCH * NHEADS), 256, 0, stream>>>(Qt, Kt, Vb, att_t);

    gemm_out<<<dim3(N_SP / 64, C_DIM / 64, BATCH), 256, 0, stream>>>(
        Wo, bo, att_t, out, x);
}

// Round 5
// 121.489 us; speedup vs baseline: 87.5446x; 1.2534x over previous
//
#include <hip/hip_runtime.h>
#include <hip/hip_bf16.h>

#define C_DIM   320
#define N_SP    2304      // 48*48
#define NHEADS  8
#define DHEAD   40
#define GROUPS  32
#define CPG     10
#define BATCH   2
#define DPAD    64        // d padded for K=32 MFMA steps
#define VPAD    48        // v rows padded to 3x16
#define W_ELEMS (C_DIM * C_DIM)   // 102400

typedef __bf16 bf16x8 __attribute__((ext_vector_type(8)));
typedef __bf16 bf16x4 __attribute__((ext_vector_type(4)));
typedef __bf16 bf16x2 __attribute__((ext_vector_type(2)));
typedef float  f32x4  __attribute__((ext_vector_type(4)));

typedef const __attribute__((address_space(1))) void* gas_ptr;
typedef __attribute__((address_space(3))) void* las_ptr;

#define MFMA16(a, b, c) __builtin_amdgcn_mfma_f32_16x16x32_bf16((a), (b), (c), 0, 0, 0)

// -------------------------------------------------------------------------
// Weight fp32 -> bf16 conversion (once per launch). grid 100 x 256.
// -------------------------------------------------------------------------
__global__ __launch_bounds__(256) void wcvt_kernel(
    const float* __restrict__ Wq, const float* __restrict__ Wk,
    const float* __restrict__ Wv, const float* __restrict__ Wo,
    __bf16* __restrict__ Wqb, __bf16* __restrict__ Wkb,
    __bf16* __restrict__ Wvb, __bf16* __restrict__ Wob)
{
    const int i = (blockIdx.x * 256 + threadIdx.x) * 4;
    f32x4 a;
    bf16x4 o;
    a = *(const f32x4*)(Wq + i);
    #pragma unroll
    for (int e = 0; e < 4; ++e) o[e] = (__bf16)a[e];
    *(bf16x4*)(Wqb + i) = o;
    a = *(const f32x4*)(Wk + i);
    #pragma unroll
    for (int e = 0; e < 4; ++e) o[e] = (__bf16)a[e];
    *(bf16x4*)(Wkb + i) = o;
    a = *(const f32x4*)(Wv + i);
    #pragma unroll
    for (int e = 0; e < 4; ++e) o[e] = (__bf16)a[e];
    *(bf16x4*)(Wvb + i) = o;
    a = *(const f32x4*)(Wo + i);
    #pragma unroll
    for (int e = 0; e < 4; ++e) o[e] = (__bf16)a[e];
    *(bf16x4*)(Wob + i) = o;
}

// -------------------------------------------------------------------------
// Zero the padding regions of Qt/Kt (d 40..63) and Vb (rows 40..47).
// grid 288 x 256 = 73728 threads.
// -------------------------------------------------------------------------
__global__ __launch_bounds__(256) void pad_zero(
    __bf16* __restrict__ Qt, __bf16* __restrict__ Kt, __bf16* __restrict__ Vb)
{
    const int t = blockIdx.x * 256 + threadIdx.x;
    const bf16x8 z = {};
    if (t < NHEADS * BATCH * N_SP) {
        const int bh = t / N_SP, n = t - bh * N_SP;
        __bf16* q = Qt + ((size_t)bh * N_SP + n) * DPAD + 40;
        __bf16* k = Kt + ((size_t)bh * N_SP + n) * DPAD + 40;
        *(bf16x8*)(q) = z; *(bf16x8*)(q + 8) = z; *(bf16x8*)(q + 16) = z;
        *(bf16x8*)(k) = z; *(bf16x8*)(k + 8) = z; *(bf16x8*)(k + 16) = z;
    } else {
        const int t2 = t - NHEADS * BATCH * N_SP;   // < 36864
        const int bh = t2 / N_SP;
        const int rem = t2 - bh * N_SP;
        const int r = rem / 288, n8 = rem - r * 288;
        *(bf16x8*)(Vb + ((size_t)bh * VPAD + 40 + r) * N_SP + n8 * 8) = z;
    }
}

// -------------------------------------------------------------------------
// GroupNorm pass 1: partial sums. grid 512 = (bg, p). Each block reduces
// CPG x 288 elements (n-slice p).
// -------------------------------------------------------------------------
__global__ __launch_bounds__(256) void gn_part(
    const float* __restrict__ x, float* __restrict__ partials)
{
    const int bid = blockIdx.x;
    const int bg = bid >> 3, p = bid & 7;
    const int b = bg >> 5, g = bg & 31;
    const float* xp = x + ((size_t)b * C_DIM + g * CPG) * N_SP + p * 288;
    const int tid = threadIdx.x;

    float sum = 0.f, sq = 0.f;
    #pragma unroll
    for (int c = 0; c < CPG; ++c) {
        for (int nl = tid; nl < 288; nl += 256) {
            const float v = xp[(size_t)c * N_SP + nl];
            sum += v; sq += v * v;
        }
    }
    #pragma unroll
    for (int off = 32; off; off >>= 1) {
        sum += __shfl_xor(sum, off);
        sq  += __shfl_xor(sq, off);
    }
    __shared__ float red[2][4];
    if ((tid & 63) == 0) { red[0][tid >> 6] = sum; red[1][tid >> 6] = sq; }
    __syncthreads();
    if (tid == 0) {
        partials[2 * bid]     = red[0][0] + red[0][1] + red[0][2] + red[0][3];
        partials[2 * bid + 1] = red[1][0] + red[1][1] + red[1][2] + red[1][3];
    }
}

// -------------------------------------------------------------------------
// GroupNorm pass 2: finalize stats + normalize + transposed bf16 write.
// grid 512 = (bg, p), same slicing.
// -------------------------------------------------------------------------
__global__ __launch_bounds__(256) void gn_apply(
    const float* __restrict__ x,
    const float* __restrict__ gamma, const float* __restrict__ beta,
    const float* __restrict__ partials, __bf16* __restrict__ xn_t)
{
    const int bid = blockIdx.x;
    const int bg = bid >> 3, p = bid & 7;
    const int b = bg >> 5, g = bg & 31;
    const int c0 = g * CPG;

    float sum = 0.f, sq = 0.f;
    #pragma unroll
    for (int i = 0; i < 8; ++i) {
        sum += partials[(bg * 8 + i) * 2];
        sq  += partials[(bg * 8 + i) * 2 + 1];
    }
    const float inv_n = 1.0f / (float)(CPG * N_SP);
    const float mean = sum * inv_n;
    const float rstd = rsqrtf(sq * inv_n - mean * mean + 1e-5f);

    float ga[CPG], be[CPG];
    #pragma unroll
    for (int c = 0; c < CPG; ++c) {
        ga[c] = gamma[c0 + c] * rstd;
        be[c] = beta[c0 + c] - mean * ga[c];
    }

    const float* xp = x + ((size_t)b * C_DIM + c0) * N_SP + p * 288;
    for (int nl = threadIdx.x; nl < 288; nl += 256) {
        const int n = p * 288 + nl;
        __bf16* dst = xn_t + ((size_t)b * N_SP + n) * C_DIM + c0;
        #pragma unroll
        for (int j = 0; j < CPG / 2; ++j) {
            const float v0 = xp[(size_t)(2 * j) * N_SP + nl]     * ga[2 * j]     + be[2 * j];
            const float v1 = xp[(size_t)(2 * j + 1) * N_SP + nl] * ga[2 * j + 1] + be[2 * j + 1];
            bf16x2 t; t[0] = (__bf16)v0; t[1] = (__bf16)v1;
            *(bf16x2*)(dst + 2 * j) = t;
        }
    }
}

// -------------------------------------------------------------------------
// Shared GEMM core: per wave computes 32x32 of Y = Wb(bf16) * Xt^T(bf16).
// acc[am][bn]: row = 4*lk+r (o-offset), col = lr (n-offset).
// -------------------------------------------------------------------------
__device__ __forceinline__ void gemm_core(
    const __bf16* __restrict__ W, const __bf16* __restrict__ Xb,
    int o0w, int n0w, int lr, int lk, f32x4 acc[2][2])
{
    const __bf16* wp0 = W + (size_t)(o0w + lr) * C_DIM + lk * 8;
    const __bf16* wp1 = wp0 + 16 * C_DIM;
    const __bf16* xp0 = Xb + (size_t)(n0w + lr) * C_DIM + lk * 8;
    const __bf16* xp1 = xp0 + 16 * C_DIM;

    #pragma unroll
    for (int k0 = 0; k0 < C_DIM; k0 += 32) {
        const bf16x8 a0 = *(const bf16x8*)(wp0 + k0);
        const bf16x8 a1 = *(const bf16x8*)(wp1 + k0);
        const bf16x8 b0 = *(const bf16x8*)(xp0 + k0);
        const bf16x8 b1 = *(const bf16x8*)(xp1 + k0);
        acc[0][0] = MFMA16(a0, b0, acc[0][0]);
        acc[0][1] = MFMA16(a0, b1, acc[0][1]);
        acc[1][0] = MFMA16(a1, b0, acc[1][0]);
        acc[1][1] = MFMA16(a1, b1, acc[1][1]);
    }
}

// -------------------------------------------------------------------------
// Fused QKV projection. grid (36, 5, 6): z = b*3 + which.
// -------------------------------------------------------------------------
__global__ __launch_bounds__(256) void gemm_qkv(
    const __bf16* __restrict__ Wqb, const __bf16* __restrict__ Wkb, const __bf16* __restrict__ Wvb,
    const float* __restrict__ bq, const float* __restrict__ bk, const float* __restrict__ bv,
    const __bf16* __restrict__ Xt,
    __bf16* __restrict__ Qt, __bf16* __restrict__ Kt, __bf16* __restrict__ Vb)
{
    const int z = blockIdx.z;
    const int b = z / 3;
    const int which = z - 3 * b;
    const __bf16* W   = (which == 0) ? Wqb : (which == 1) ? Wkb : Wvb;
    const float* bias = (which == 0) ? bq : (which == 1) ? bk : bv;
    const float scale = (which == 0) ? 0.15811388300841897f : 1.0f;

    const int n0 = blockIdx.x * 64, o0 = blockIdx.y * 64;
    const int tid = threadIdx.x, wave = tid >> 6, lane = tid & 63;
    const int lr = lane & 15, lk = lane >> 4;
    const int wm = wave >> 1, wn = wave & 1;

    f32x4 acc[2][2] = {};
    gemm_core(W, Xt + (size_t)b * N_SP * C_DIM, o0 + wm * 32, n0 + wn * 32, lr, lk, acc);

    #pragma unroll
    for (int am = 0; am < 2; ++am) {
        #pragma unroll
        for (int r = 0; r < 4; ++r) {
            const int o = o0 + wm * 32 + am * 16 + 4 * lk + r;
            const float bv_ = bias[o];
            const int h = o / DHEAD, d = o - h * DHEAD;
            const int bh = b * NHEADS + h;
            #pragma unroll
            for (int bn = 0; bn < 2; ++bn) {
                const int n = n0 + wn * 32 + bn * 16 + lr;
                const float v = (acc[am][bn][r] + bv_) * scale;
                if (which < 2) {
                    __bf16* dst = (which == 0) ? Qt : Kt;
                    dst[((size_t)bh * N_SP + n) * DPAD + d] = (__bf16)v;
                } else {
                    Vb[((size_t)bh * VPAD + d) * N_SP + n] = (__bf16)v;
                }
            }
        }
    }
}

// -------------------------------------------------------------------------
// Output projection: out[b][o][n] = Wo * att_t^T + bo + x  (fp32 out)
// -------------------------------------------------------------------------
__global__ __launch_bounds__(256) void gemm_out(
    const __bf16* __restrict__ Wob, const float* __restrict__ bo,
    const __bf16* __restrict__ att_t,
    float* __restrict__ Y, const float* __restrict__ resid)
{
    const int b = blockIdx.z;
    const int n0 = blockIdx.x * 64, o0 = blockIdx.y * 64;
    const int tid = threadIdx.x, wave = tid >> 6, lane = tid & 63;
    const int lr = lane & 15, lk = lane >> 4;
    const int wm = wave >> 1, wn = wave & 1;

    f32x4 acc[2][2] = {};
    gemm_core(Wob, att_t + (size_t)b * N_SP * C_DIM, o0 + wm * 32, n0 + wn * 32, lr, lk, acc);

    #pragma unroll
    for (int am = 0; am < 2; ++am) {
        #pragma unroll
        for (int r = 0; r < 4; ++r) {
            const int o = o0 + wm * 32 + am * 16 + 4 * lk + r;
            const float bv_ = bo[o];
            #pragma unroll
            for (int bn = 0; bn < 2; ++bn) {
                const int n = n0 + wn * 32 + bn * 16 + lr;
                const size_t idx = ((size_t)b * C_DIM + o) * N_SP + n;
                Y[idx] = acc[am][bn][r] + bv_ + resid[idx];
            }
        }
    }
}

// -------------------------------------------------------------------------
// Flash attention, block-cooperative KV staging (double-buffered LDS via
// global_load_lds with pre-swizzled sources), defer-max, setprio on MFMA.
// -------------------------------------------------------------------------
__global__ __launch_bounds__(256) void attn_mfma(
    const __bf16* __restrict__ Qt,
    const __bf16* __restrict__ Kt,
    const __bf16* __restrict__ Vb,
    __bf16* __restrict__ att_t)
{
    __shared__ __align__(16) __bf16 Ks[2][64 * DPAD];   // 2 x 8KB
    __shared__ __align__(16) __bf16 Vs[2][VPAD * 64];   // 2 x 6KB
    __shared__ __align__(16) __bf16 Ps[4][16 * 64];     // per-wave P^T

    const int bh = blockIdx.y, b = bh >> 3, h = bh & 7;
    const int tid = threadIdx.x, wave = tid >> 6, lane = tid & 63;
    const int lr = lane & 15, lk = lane >> 4;
    const int swz = (lr & 7) << 4;
    const int i0 = (blockIdx.x * 4 + wave) * 16;

    const char* Kg = (const char*)(Kt + (size_t)bh * N_SP * DPAD);
    const char* Vg = (const char*)(Vb + (size_t)bh * VPAD * N_SP);

    const __bf16* Qp = Qt + ((size_t)bh * N_SP + i0 + lr) * DPAD + lk * 8;
    const bf16x8 qb0 = *(const bf16x8*)(Qp);
    const bf16x8 qb1 = *(const bf16x8*)(Qp + 32);

    f32x4 O[3] = {};
    float m = -1e30f, lsum = 0.f;

    auto stage = [&](int bufi, int t) {
        const int j0 = t * 64;
        #pragma unroll
        for (int i2 = 0; i2 < 2; ++i2) {
            const int chunk = wave * 2 + i2;
            const int L = chunk * 1024 + lane * 16;
            const int src = L ^ (((L >> 7) & 7) << 4);
            __builtin_amdgcn_global_load_lds(
                (gas_ptr)(Kg + (size_t)j0 * 128 + src),
                (las_ptr)((char*)Ks[bufi] + chunk * 1024),
                16, 0, 0);
        }
        for (int i2 = wave; i2 < 6; i2 += 4) {
            const int row = i2 * 8 + (lane >> 3);
            const int csw = ((lane & 7) << 4) ^ ((row & 7) << 4);
            __builtin_amdgcn_global_load_lds(
                (gas_ptr)(Vg + ((size_t)row * N_SP + j0) * 2 + csw),
                (las_ptr)((char*)Vs[bufi] + i2 * 1024),
                16, 0, 0);
        }
    };

    stage(0, 0);
    __syncthreads();

    for (int t = 0; t < 36; ++t) {
        const int bufi = t & 1;
        if (t + 1 < 36) stage(bufi ^ 1, t + 1);

        const char* ks = (const char*)Ks[bufi];
        const char* vs = (const char*)Vs[bufi];
        char* ps = (char*)Ps[wave];

        // ---- S^T = K · Q ----
        f32x4 S[4];
        __builtin_amdgcn_s_setprio(1);
        #pragma unroll
        for (int kt = 0; kt < 4; ++kt) {
            const int rowb = (kt * 16 + lr) * 128;
            const bf16x8 k0 = *(const bf16x8*)(ks + rowb + ((lk * 16) ^ swz));
            const bf16x8 k1 = *(const bf16x8*)(ks + rowb + ((64 + lk * 16) ^ swz));
            f32x4 zz = {};
            zz = MFMA16(k0, qb0, zz);
            S[kt] = MFMA16(k1, qb1, zz);
        }
        __builtin_amdgcn_s_setprio(0);

        // ---- online softmax with defer-max (THR = 8) ----
        float tmax = -1e30f;
        #pragma unroll
        for (int kt = 0; kt < 4; ++kt)
            #pragma unroll
            for (int r = 0; r < 4; ++r) tmax = fmaxf(tmax, S[kt][r]);
        tmax = fmaxf(tmax, __shfl_xor(tmax, 16));
        tmax = fmaxf(tmax, __shfl_xor(tmax, 32));

        const bool grow = __any(tmax > m + 8.f);
        const float mn = grow ? fmaxf(m, tmax) : m;
        float rsum = 0.f;
        #pragma unroll
        for (int kt = 0; kt < 4; ++kt) {
            bf16x4 w;
            #pragma unroll
            for (int r = 0; r < 4; ++r) {
                const float p = __expf(S[kt][r] - mn);
                rsum += p;
                w[r] = (__bf16)p;
            }
            *(bf16x4*)(ps + lr * 128 + ((kt * 32 + lk * 8) ^ swz)) = w;
        }
        rsum += __shfl_xor(rsum, 16);
        rsum += __shfl_xor(rsum, 32);
        if (grow) {
            const float f = __expf(m - mn);
            lsum = lsum * f + rsum;
            m = mn;
            #pragma unroll
            for (int dt = 0; dt < 3; ++dt)
                #pragma unroll
                for (int r = 0; r < 4; ++r) O[dt][r] *= f;
        } else {
            lsum += rsum;
        }

        // ---- O^T += V^T · P^T ----
        __builtin_amdgcn_s_setprio(1);
        #pragma unroll
        for (int hh = 0; hh < 2; ++hh) {
            const bf16x8 pb = *(const bf16x8*)(ps + lr * 128 + ((hh * 64 + lk * 16) ^ swz));
            #pragma unroll
            for (int dt = 0; dt < 3; ++dt) {
                const bf16x8 va = *(const bf16x8*)(vs + (dt * 16 + lr) * 128 + ((hh * 64 + lk * 16) ^ swz));
                O[dt] = MFMA16(va, pb, O[dt]);
            }
        }
        __builtin_amdgcn_s_setprio(0);

        __syncthreads();
    }

    // ---- epilogue ----
    const float inv = 1.0f / lsum;
    __bf16* op = att_t + ((size_t)b * N_SP + i0 + lr) * C_DIM + h * DHEAD;
    bf16x4 o0v, o1v, o2v;
    #pragma unroll
    for (int r = 0; r < 4; ++r) {
        o0v[r] = (__bf16)(O[0][r] * inv);
        o1v[r] = (__bf16)(O[1][r] * inv);
        o2v[r] = (__bf16)(O[2][r] * inv);
    }
    *(bf16x4*)(op + 4 * lk)      = o0v;
    *(bf16x4*)(op + 16 + 4 * lk) = o1v;
    if (lk < 2)
        *(bf16x4*)(op + 32 + 4 * lk) = o2v;
}

// -------------------------------------------------------------------------
extern "C" void kernel_launch(void* const* d_in, const int* in_sizes, int n_in,
                              void* d_out, int out_size, void* d_ws, size_t ws_size,
                              hipStream_t stream) {
    const float* x     = (const float*)d_in[0];
    const float* gamma = (const float*)d_in[1];
    const float* beta  = (const float*)d_in[2];
    const float* Wq    = (const float*)d_in[3];
    const float* bq    = (const float*)d_in[4];
    const float* Wk    = (const float*)d_in[5];
    const float* bk    = (const float*)d_in[6];
    const float* Wv    = (const float*)d_in[7];
    const float* bv    = (const float*)d_in[8];
    const float* Wo    = (const float*)d_in[9];
    const float* bo    = (const float*)d_in[10];

    float* out = (float*)d_out;

    const size_t S_NC  = (size_t)BATCH * N_SP * C_DIM;          // 1,474,560
    const size_t S_QK  = (size_t)BATCH * NHEADS * N_SP * DPAD;  // 2,359,296
    const size_t S_V   = (size_t)BATCH * NHEADS * VPAD * N_SP;  // 1,769,472

    __bf16* xn_t  = (__bf16*)d_ws;
    __bf16* Qt    = xn_t + S_NC;
    __bf16* Kt    = Qt + S_QK;
    __bf16* Vb    = Kt + S_QK;
    __bf16* att_t = Vb + S_V;
    __bf16* Wqb   = att_t + S_NC;
    __bf16* Wkb   = Wqb + W_ELEMS;
    __bf16* Wvb   = Wkb + W_ELEMS;
    __bf16* Wob   = Wvb + W_ELEMS;
    float* partials = (float*)(Wob + W_ELEMS);   // 1024 floats

    wcvt_kernel<<<W_ELEMS / (256 * 4), 256, 0, stream>>>(
        Wq, Wk, Wv, Wo, Wqb, Wkb, Wvb, Wob);

    gn_part<<<512, 256, 0, stream>>>(x, partials);
    gn_apply<<<512, 256, 0, stream>>>(x, gamma, beta, partials, xn_t);

    pad_zero<<<288, 256, 0, stream>>>(Qt, Kt, Vb);

    gemm_qkv<<<dim3(N_SP / 64, C_DIM / 64, 3 * BATCH), 256, 0, stream>>>(
        Wqb, Wkb, Wvb, bq, bk, bv, xn_t, Qt, Kt, Vb);

    attn_mfma<<<dim3(N_SP / 64, BATCH * NHEADS), 256, 0, stream>>>(Qt, Kt, Vb, att_t);

    gemm_out<<<dim3(N_SP / 64, C_DIM / 64, BATCH), 256, 0, stream>>>(
        Wob, bo, att_t, out, x);
}

// Round 6
// 118.542 us; speedup vs baseline: 89.7213x; 1.0249x over previous
//
#include <hip/hip_runtime.h>
#include <hip/hip_bf16.h>

#define C_DIM   320
#define N_SP    2304      // 48*48
#define NHEADS  8
#define DHEAD   40
#define GROUPS  32
#define CPG     10
#define BATCH   2
#define DPAD    64        // d padded for K=32 MFMA steps
#define VPAD    48        // v rows padded to 3x16
#define W_ELEMS (C_DIM * C_DIM)   // 102400
#define NSPLIT  2
#define TILES_PER_SPLIT 18        // 36 KV tiles / NSPLIT

typedef __bf16 bf16x8 __attribute__((ext_vector_type(8)));
typedef __bf16 bf16x4 __attribute__((ext_vector_type(4)));
typedef __bf16 bf16x2 __attribute__((ext_vector_type(2)));
typedef float  f32x4  __attribute__((ext_vector_type(4)));

typedef const __attribute__((address_space(1))) void* gas_ptr;
typedef __attribute__((address_space(3))) void* las_ptr;

#define MFMA16(a, b, c) __builtin_amdgcn_mfma_f32_16x16x32_bf16((a), (b), (c), 0, 0, 0)

// -------------------------------------------------------------------------
// prep: fused weight fp32->bf16 conversion + Q/K/V pad zeroing.
// grid 388: blocks 0..99 = wcvt, 100..387 = pad_zero.
// -------------------------------------------------------------------------
__global__ __launch_bounds__(256) void prep_kernel(
    const float* __restrict__ Wq, const float* __restrict__ Wk,
    const float* __restrict__ Wv, const float* __restrict__ Wo,
    __bf16* __restrict__ Wqb, __bf16* __restrict__ Wkb,
    __bf16* __restrict__ Wvb, __bf16* __restrict__ Wob,
    __bf16* __restrict__ Qt, __bf16* __restrict__ Kt, __bf16* __restrict__ Vb)
{
    if (blockIdx.x < 100) {
        const int i = (blockIdx.x * 256 + threadIdx.x) * 4;
        f32x4 a;
        bf16x4 o;
        a = *(const f32x4*)(Wq + i);
        #pragma unroll
        for (int e = 0; e < 4; ++e) o[e] = (__bf16)a[e];
        *(bf16x4*)(Wqb + i) = o;
        a = *(const f32x4*)(Wk + i);
        #pragma unroll
        for (int e = 0; e < 4; ++e) o[e] = (__bf16)a[e];
        *(bf16x4*)(Wkb + i) = o;
        a = *(const f32x4*)(Wv + i);
        #pragma unroll
        for (int e = 0; e < 4; ++e) o[e] = (__bf16)a[e];
        *(bf16x4*)(Wvb + i) = o;
        a = *(const f32x4*)(Wo + i);
        #pragma unroll
        for (int e = 0; e < 4; ++e) o[e] = (__bf16)a[e];
        *(bf16x4*)(Wob + i) = o;
    } else {
        const int t = (blockIdx.x - 100) * 256 + threadIdx.x;
        const bf16x8 z = {};
        if (t < NHEADS * BATCH * N_SP) {
            const int bh = t / N_SP, n = t - bh * N_SP;
            __bf16* q = Qt + ((size_t)bh * N_SP + n) * DPAD + 40;
            __bf16* k = Kt + ((size_t)bh * N_SP + n) * DPAD + 40;
            *(bf16x8*)(q) = z; *(bf16x8*)(q + 8) = z; *(bf16x8*)(q + 16) = z;
            *(bf16x8*)(k) = z; *(bf16x8*)(k + 8) = z; *(bf16x8*)(k + 16) = z;
        } else {
            const int t2 = t - NHEADS * BATCH * N_SP;   // < 36864
            const int bh = t2 / N_SP;
            const int rem = t2 - bh * N_SP;
            const int r = rem / 288, n8 = rem - r * 288;
            *(bf16x8*)(Vb + ((size_t)bh * VPAD + 40 + r) * N_SP + n8 * 8) = z;
        }
    }
}

// -------------------------------------------------------------------------
// GroupNorm pass 1: partial sums. grid 512 = (bg, p).
// -------------------------------------------------------------------------
__global__ __launch_bounds__(256) void gn_part(
    const float* __restrict__ x, float* __restrict__ partials)
{
    const int bid = blockIdx.x;
    const int bg = bid >> 3, p = bid & 7;
    const int b = bg >> 5, g = bg & 31;
    const float* xp = x + ((size_t)b * C_DIM + g * CPG) * N_SP + p * 288;
    const int tid = threadIdx.x;

    float sum = 0.f, sq = 0.f;
    #pragma unroll
    for (int c = 0; c < CPG; ++c) {
        for (int nl = tid; nl < 288; nl += 256) {
            const float v = xp[(size_t)c * N_SP + nl];
            sum += v; sq += v * v;
        }
    }
    #pragma unroll
    for (int off = 32; off; off >>= 1) {
        sum += __shfl_xor(sum, off);
        sq  += __shfl_xor(sq, off);
    }
    __shared__ float red[2][4];
    if ((tid & 63) == 0) { red[0][tid >> 6] = sum; red[1][tid >> 6] = sq; }
    __syncthreads();
    if (tid == 0) {
        partials[2 * bid]     = red[0][0] + red[0][1] + red[0][2] + red[0][3];
        partials[2 * bid + 1] = red[1][0] + red[1][1] + red[1][2] + red[1][3];
    }
}

// -------------------------------------------------------------------------
// GroupNorm pass 2: finalize + normalize + transposed bf16 write.
// -------------------------------------------------------------------------
__global__ __launch_bounds__(256) void gn_apply(
    const float* __restrict__ x,
    const float* __restrict__ gamma, const float* __restrict__ beta,
    const float* __restrict__ partials, __bf16* __restrict__ xn_t)
{
    const int bid = blockIdx.x;
    const int bg = bid >> 3, p = bid & 7;
    const int b = bg >> 5, g = bg & 31;
    const int c0 = g * CPG;

    float sum = 0.f, sq = 0.f;
    #pragma unroll
    for (int i = 0; i < 8; ++i) {
        sum += partials[(bg * 8 + i) * 2];
        sq  += partials[(bg * 8 + i) * 2 + 1];
    }
    const float inv_n = 1.0f / (float)(CPG * N_SP);
    const float mean = sum * inv_n;
    const float rstd = rsqrtf(sq * inv_n - mean * mean + 1e-5f);

    float ga[CPG], be[CPG];
    #pragma unroll
    for (int c = 0; c < CPG; ++c) {
        ga[c] = gamma[c0 + c] * rstd;
        be[c] = beta[c0 + c] - mean * ga[c];
    }

    const float* xp = x + ((size_t)b * C_DIM + c0) * N_SP + p * 288;
    for (int nl = threadIdx.x; nl < 288; nl += 256) {
        const int n = p * 288 + nl;
        __bf16* dst = xn_t + ((size_t)b * N_SP + n) * C_DIM + c0;
        #pragma unroll
        for (int j = 0; j < CPG / 2; ++j) {
            const float v0 = xp[(size_t)(2 * j) * N_SP + nl]     * ga[2 * j]     + be[2 * j];
            const float v1 = xp[(size_t)(2 * j + 1) * N_SP + nl] * ga[2 * j + 1] + be[2 * j + 1];
            bf16x2 t; t[0] = (__bf16)v0; t[1] = (__bf16)v1;
            *(bf16x2*)(dst + 2 * j) = t;
        }
    }
}

// -------------------------------------------------------------------------
// Shared GEMM core: per wave computes 32x32 of Y = Wb(bf16) * Xt^T(bf16).
// -------------------------------------------------------------------------
__device__ __forceinline__ void gemm_core(
    const __bf16* __restrict__ W, const __bf16* __restrict__ Xb,
    int o0w, int n0w, int lr, int lk, f32x4 acc[2][2])
{
    const __bf16* wp0 = W + (size_t)(o0w + lr) * C_DIM + lk * 8;
    const __bf16* wp1 = wp0 + 16 * C_DIM;
    const __bf16* xp0 = Xb + (size_t)(n0w + lr) * C_DIM + lk * 8;
    const __bf16* xp1 = xp0 + 16 * C_DIM;

    #pragma unroll
    for (int k0 = 0; k0 < C_DIM; k0 += 32) {
        const bf16x8 a0 = *(const bf16x8*)(wp0 + k0);
        const bf16x8 a1 = *(const bf16x8*)(wp1 + k0);
        const bf16x8 b0 = *(const bf16x8*)(xp0 + k0);
        const bf16x8 b1 = *(const bf16x8*)(xp1 + k0);
        acc[0][0] = MFMA16(a0, b0, acc[0][0]);
        acc[0][1] = MFMA16(a0, b1, acc[0][1]);
        acc[1][0] = MFMA16(a1, b0, acc[1][0]);
        acc[1][1] = MFMA16(a1, b1, acc[1][1]);
    }
}

// -------------------------------------------------------------------------
// Fused QKV projection. grid (36, 5, 6): z = b*3 + which.
// -------------------------------------------------------------------------
__global__ __launch_bounds__(256) void gemm_qkv(
    const __bf16* __restrict__ Wqb, const __bf16* __restrict__ Wkb, const __bf16* __restrict__ Wvb,
    const float* __restrict__ bq, const float* __restrict__ bk, const float* __restrict__ bv,
    const __bf16* __restrict__ Xt,
    __bf16* __restrict__ Qt, __bf16* __restrict__ Kt, __bf16* __restrict__ Vb)
{
    const int z = blockIdx.z;
    const int b = z / 3;
    const int which = z - 3 * b;
    const __bf16* W   = (which == 0) ? Wqb : (which == 1) ? Wkb : Wvb;
    const float* bias = (which == 0) ? bq : (which == 1) ? bk : bv;
    const float scale = (which == 0) ? 0.15811388300841897f : 1.0f;

    const int n0 = blockIdx.x * 64, o0 = blockIdx.y * 64;
    const int tid = threadIdx.x, wave = tid >> 6, lane = tid & 63;
    const int lr = lane & 15, lk = lane >> 4;
    const int wm = wave >> 1, wn = wave & 1;

    f32x4 acc[2][2] = {};
    gemm_core(W, Xt + (size_t)b * N_SP * C_DIM, o0 + wm * 32, n0 + wn * 32, lr, lk, acc);

    #pragma unroll
    for (int am = 0; am < 2; ++am) {
        #pragma unroll
        for (int r = 0; r < 4; ++r) {
            const int o = o0 + wm * 32 + am * 16 + 4 * lk + r;
            const float bv_ = bias[o];
            const int h = o / DHEAD, d = o - h * DHEAD;
            const int bh = b * NHEADS + h;
            #pragma unroll
            for (int bn = 0; bn < 2; ++bn) {
                const int n = n0 + wn * 32 + bn * 16 + lr;
                const float v = (acc[am][bn][r] + bv_) * scale;
                if (which < 2) {
                    __bf16* dst = (which == 0) ? Qt : Kt;
                    dst[((size_t)bh * N_SP + n) * DPAD + d] = (__bf16)v;
                } else {
                    Vb[((size_t)bh * VPAD + d) * N_SP + n] = (__bf16)v;
                }
            }
        }
    }
}

// -------------------------------------------------------------------------
// Output projection: out[b][o][n] = Wo * att_t^T + bo + x  (fp32 out)
// -------------------------------------------------------------------------
__global__ __launch_bounds__(256) void gemm_out(
    const __bf16* __restrict__ Wob, const float* __restrict__ bo,
    const __bf16* __restrict__ att_t,
    float* __restrict__ Y, const float* __restrict__ resid)
{
    const int b = blockIdx.z;
    const int n0 = blockIdx.x * 64, o0 = blockIdx.y * 64;
    const int tid = threadIdx.x, wave = tid >> 6, lane = tid & 63;
    const int lr = lane & 15, lk = lane >> 4;
    const int wm = wave >> 1, wn = wave & 1;

    f32x4 acc[2][2] = {};
    gemm_core(Wob, att_t + (size_t)b * N_SP * C_DIM, o0 + wm * 32, n0 + wn * 32, lr, lk, acc);

    #pragma unroll
    for (int am = 0; am < 2; ++am) {
        #pragma unroll
        for (int r = 0; r < 4; ++r) {
            const int o = o0 + wm * 32 + am * 16 + 4 * lk + r;
            const float bv_ = bo[o];
            #pragma unroll
            for (int bn = 0; bn < 2; ++bn) {
                const int n = n0 + wn * 32 + bn * 16 + lr;
                const size_t idx = ((size_t)b * C_DIM + o) * N_SP + n;
                Y[idx] = acc[am][bn][r] + bv_ + resid[idx];
            }
        }
    }
}

// -------------------------------------------------------------------------
// Flash attention, split-KV: grid (36, 16, 2). Block s handles KV tiles
// [s*18, s*18+18) and writes unnormalized partials (O, m, lsum) to
// part[s][bh][48][N_SP] (slot-major f32; slots 0..39 = O_d, 40 = m, 41 = l).
// -------------------------------------------------------------------------
__global__ __launch_bounds__(256) void attn_mfma(
    const __bf16* __restrict__ Qt,
    const __bf16* __restrict__ Kt,
    const __bf16* __restrict__ Vb,
    float* __restrict__ part)
{
    __shared__ __align__(16) __bf16 Ks[2][64 * DPAD];   // 2 x 8KB
    __shared__ __align__(16) __bf16 Vs[2][VPAD * 64];   // 2 x 6KB
    __shared__ __align__(16) __bf16 Ps[4][16 * 64];     // per-wave P^T

    const int bh = blockIdx.y;
    const int s  = blockIdx.z;
    const int tid = threadIdx.x, wave = tid >> 6, lane = tid & 63;
    const int lr = lane & 15, lk = lane >> 4;
    const int swz = (lr & 7) << 4;
    const int i0 = (blockIdx.x * 4 + wave) * 16;

    const char* Kg = (const char*)(Kt + (size_t)bh * N_SP * DPAD);
    const char* Vg = (const char*)(Vb + (size_t)bh * VPAD * N_SP);

    const __bf16* Qp = Qt + ((size_t)bh * N_SP + i0 + lr) * DPAD + lk * 8;
    const bf16x8 qb0 = *(const bf16x8*)(Qp);
    const bf16x8 qb1 = *(const bf16x8*)(Qp + 32);

    f32x4 O[3] = {};
    float m = -1e30f, lsum = 0.f;

    auto stage = [&](int bufi, int t) {
        const int j0 = t * 64;
        #pragma unroll
        for (int i2 = 0; i2 < 2; ++i2) {
            const int chunk = wave * 2 + i2;
            const int L = chunk * 1024 + lane * 16;
            const int src = L ^ (((L >> 7) & 7) << 4);
            __builtin_amdgcn_global_load_lds(
                (gas_ptr)(Kg + (size_t)j0 * 128 + src),
                (las_ptr)((char*)Ks[bufi] + chunk * 1024),
                16, 0, 0);
        }
        for (int i2 = wave; i2 < 6; i2 += 4) {
            const int row = i2 * 8 + (lane >> 3);
            const int csw = ((lane & 7) << 4) ^ ((row & 7) << 4);
            __builtin_amdgcn_global_load_lds(
                (gas_ptr)(Vg + ((size_t)row * N_SP + j0) * 2 + csw),
                (las_ptr)((char*)Vs[bufi] + i2 * 1024),
                16, 0, 0);
        }
    };

    const int t0 = s * TILES_PER_SPLIT;
    const int t1 = t0 + TILES_PER_SPLIT;

    stage(0, t0);
    __syncthreads();

    for (int t = t0; t < t1; ++t) {
        const int bufi = t & 1;
        if (t + 1 < t1) stage(bufi ^ 1, t + 1);

        const char* ks = (const char*)Ks[bufi];
        const char* vs = (const char*)Vs[bufi];
        char* ps = (char*)Ps[wave];

        // ---- S^T = K · Q ----
        f32x4 S[4];
        __builtin_amdgcn_s_setprio(1);
        #pragma unroll
        for (int kt = 0; kt < 4; ++kt) {
            const int rowb = (kt * 16 + lr) * 128;
            const bf16x8 k0 = *(const bf16x8*)(ks + rowb + ((lk * 16) ^ swz));
            const bf16x8 k1 = *(const bf16x8*)(ks + rowb + ((64 + lk * 16) ^ swz));
            f32x4 zz = {};
            zz = MFMA16(k0, qb0, zz);
            S[kt] = MFMA16(k1, qb1, zz);
        }
        __builtin_amdgcn_s_setprio(0);

        // ---- online softmax with defer-max (THR = 8) ----
        float tmax = -1e30f;
        #pragma unroll
        for (int kt = 0; kt < 4; ++kt)
            #pragma unroll
            for (int r = 0; r < 4; ++r) tmax = fmaxf(tmax, S[kt][r]);
        tmax = fmaxf(tmax, __shfl_xor(tmax, 16));
        tmax = fmaxf(tmax, __shfl_xor(tmax, 32));

        const bool grow = __any(tmax > m + 8.f);
        const float mn = grow ? fmaxf(m, tmax) : m;
        float rsum = 0.f;
        #pragma unroll
        for (int kt = 0; kt < 4; ++kt) {
            bf16x4 w;
            #pragma unroll
            for (int r = 0; r < 4; ++r) {
                const float p = __expf(S[kt][r] - mn);
                rsum += p;
                w[r] = (__bf16)p;
            }
            *(bf16x4*)(ps + lr * 128 + ((kt * 32 + lk * 8) ^ swz)) = w;
        }
        rsum += __shfl_xor(rsum, 16);
        rsum += __shfl_xor(rsum, 32);
        if (grow) {
            const float f = __expf(m - mn);
            lsum = lsum * f + rsum;
            m = mn;
            #pragma unroll
            for (int dt = 0; dt < 3; ++dt)
                #pragma unroll
                for (int r = 0; r < 4; ++r) O[dt][r] *= f;
        } else {
            lsum += rsum;
        }

        // ---- O^T += V^T · P^T ----
        __builtin_amdgcn_s_setprio(1);
        #pragma unroll
        for (int hh = 0; hh < 2; ++hh) {
            const bf16x8 pb = *(const bf16x8*)(ps + lr * 128 + ((hh * 64 + lk * 16) ^ swz));
            #pragma unroll
            for (int dt = 0; dt < 3; ++dt) {
                const bf16x8 va = *(const bf16x8*)(vs + (dt * 16 + lr) * 128 + ((hh * 64 + lk * 16) ^ swz));
                O[dt] = MFMA16(va, pb, O[dt]);
            }
        }
        __builtin_amdgcn_s_setprio(0);

        __syncthreads();
    }

    // ---- epilogue: write partials (unnormalized O, m, lsum) ----
    float* pb = part + ((size_t)(s * 16 + bh) * 48) * N_SP + (i0 + lr);
    #pragma unroll
    for (int dt = 0; dt < 3; ++dt) {
        #pragma unroll
        for (int r = 0; r < 4; ++r) {
            const int d = dt * 16 + 4 * lk + r;
            if (dt < 2 || lk < 2)
                pb[(size_t)d * N_SP] = O[dt][r];
        }
    }
    if (lk == 2) {
        pb[(size_t)40 * N_SP] = m;
        pb[(size_t)41 * N_SP] = lsum;
    }
}

// -------------------------------------------------------------------------
// Combine the two KV-split partials -> att_t [B][N][320] bf16.
// grid (9, 16) x 256: one thread per (bh, q).
// -------------------------------------------------------------------------
__global__ __launch_bounds__(256) void attn_combine(
    const float* __restrict__ part, __bf16* __restrict__ att_t)
{
    const int q = blockIdx.x * 256 + threadIdx.x;
    const int bh = blockIdx.y, b = bh >> 3, h = bh & 7;

    const float* p0 = part + ((size_t)bh * 48) * N_SP + q;
    const float* p1 = part + ((size_t)(16 + bh) * 48) * N_SP + q;

    const float m0 = p0[(size_t)40 * N_SP], l0 = p0[(size_t)41 * N_SP];
    const float m1 = p1[(size_t)40 * N_SP], l1 = p1[(size_t)41 * N_SP];
    const float M  = fmaxf(m0, m1);
    const float w0 = __expf(m0 - M), w1 = __expf(m1 - M);
    const float inv = 1.0f / (l0 * w0 + l1 * w1);
    const float a0 = w0 * inv, a1 = w1 * inv;

    __bf16* op = att_t + ((size_t)b * N_SP + q) * C_DIM + h * DHEAD;
    #pragma unroll
    for (int d = 0; d < DHEAD; ++d)
        op[d] = (__bf16)(p0[(size_t)d * N_SP] * a0 + p1[(size_t)d * N_SP] * a1);
}

// -------------------------------------------------------------------------
extern "C" void kernel_launch(void* const* d_in, const int* in_sizes, int n_in,
                              void* d_out, int out_size, void* d_ws, size_t ws_size,
                              hipStream_t stream) {
    const float* x     = (const float*)d_in[0];
    const float* gamma = (const float*)d_in[1];
    const float* beta  = (const float*)d_in[2];
    const float* Wq    = (const float*)d_in[3];
    const float* bq    = (const float*)d_in[4];
    const float* Wk    = (const float*)d_in[5];
    const float* bk    = (const float*)d_in[6];
    const float* Wv    = (const float*)d_in[7];
    const float* bv    = (const float*)d_in[8];
    const float* Wo    = (const float*)d_in[9];
    const float* bo    = (const float*)d_in[10];

    float* out = (float*)d_out;

    const size_t S_NC  = (size_t)BATCH * N_SP * C_DIM;          // 1,474,560
    const size_t S_QK  = (size_t)BATCH * NHEADS * N_SP * DPAD;  // 2,359,296
    const size_t S_V   = (size_t)BATCH * NHEADS * VPAD * N_SP;  // 1,769,472

    __bf16* xn_t  = (__bf16*)d_ws;
    __bf16* Qt    = xn_t + S_NC;
    __bf16* Kt    = Qt + S_QK;
    __bf16* Vb    = Kt + S_QK;
    __bf16* att_t = Vb + S_V;
    __bf16* Wqb   = att_t + S_NC;
    __bf16* Wkb   = Wqb + W_ELEMS;
    __bf16* Wvb   = Wkb + W_ELEMS;
    __bf16* Wob   = Wvb + W_ELEMS;
    float* partials = (float*)(Wob + W_ELEMS);           // 1024 floats
    float* part     = partials + 1024;                   // 2*16*48*2304 f32

    prep_kernel<<<388, 256, 0, stream>>>(
        Wq, Wk, Wv, Wo, Wqb, Wkb, Wvb, Wob, Qt, Kt, Vb);

    gn_part<<<512, 256, 0, stream>>>(x, partials);
    gn_apply<<<512, 256, 0, stream>>>(x, gamma, beta, partials, xn_t);

    gemm_qkv<<<dim3(N_SP / 64, C_DIM / 64, 3 * BATCH), 256, 0, stream>>>(
        Wqb, Wkb, Wvb, bq, bk, bv, xn_t, Qt, Kt, Vb);

    attn_mfma<<<dim3(N_SP / 64, BATCH * NHEADS, NSPLIT), 256, 0, stream>>>(
        Qt, Kt, Vb, part);

    attn_combine<<<dim3(N_SP / 256, BATCH * NHEADS), 256, 0, stream>>>(part, att_t);

    gemm_out<<<dim3(N_SP / 64, C_DIM / 64, BATCH), 256, 0, stream>>>(
        Wob, bo, att_t, out, x);
}